// Round 1
// baseline (45405.801 us; speedup 1.0000x reference)
//
#include <hip/hip_runtime.h>
#include <hip/hip_bf16.h>
#include <math.h>

#define NTHREADS 256

static constexpr int cB  = 64;
static constexpr int cH  = 56;
static constexpr int cW  = 56;
static constexpr int cC  = 192;
static constexpr int cNH = 6;
static constexpr int cN  = 49;   // tokens per window
static constexpr int cHD = 32;   // head dim
static constexpr float cSCALE = 0.17677669529663687f; // 32^-0.5

__device__ __forceinline__ float bf2f(unsigned short u) {
    union { unsigned int i; float f; } c; c.i = ((unsigned int)u) << 16; return c.f;
}
__device__ __forceinline__ unsigned short f2bf(float f) {
    union { float f; unsigned int i; } c; c.f = f;
    unsigned int r = c.i + (0x7fffu + ((c.i >> 16) & 1u));
    return (unsigned short)(r >> 16);
}

// ---------------- Kernel A: LN1 + shift/window + attention + proj + residual ----------------
struct SA {
    unsigned short win[cN][cC];   // 18816 B  (normalized, shifted window tokens)
    unsigned short po[cN][cC];    // 18816 B  (attention output, all heads)
    unsigned short q[cN][cHD];    // 3136 B
    unsigned short k[cN][cHD];    // 3136 B
    unsigned short v[cN][cHD];    // 3136 B
    float          s[cN][cN];     // 9604 B
};                                // total 56644 B -> 2 blocks/CU

__global__ __launch_bounds__(NTHREADS)
void swin_attn(const float* __restrict__ x, const float* __restrict__ mask,
               const float* __restrict__ g1, const float* __restrict__ b1,
               const float* __restrict__ qkvw, const float* __restrict__ qkvb,
               const float* __restrict__ rpb, const float* __restrict__ pw,
               const float* __restrict__ pb, float* __restrict__ y)
{
    __shared__ SA L;
    const int w = blockIdx.x;
    const int bb = w >> 6, wi = w & 63;
    const int wh = wi >> 3, ww = wi & 7;
    const int tid = threadIdx.x, lane = tid & 63, wave = tid >> 6;

    // ---- Phase 1: LN1 + shifted gather into win (bf16) ----
    for (int r = wave; r < cN; r += 4) {
        const int p = r / 7, q7 = r - p * 7;
        int i2 = wh * 7 + p + 3;  if (i2 >= 56) i2 -= 56;
        int j2 = ww * 7 + q7 + 3; if (j2 >= 56) j2 -= 56;
        const float* xr = x + ((size_t)(bb * 56 + i2) * 56 + j2) * cC;
        const float a0 = xr[lane], a1 = xr[lane + 64], a2 = xr[lane + 128];
        float sm = a0 + a1 + a2, sq = a0 * a0 + a1 * a1 + a2 * a2;
        #pragma unroll
        for (int o = 32; o > 0; o >>= 1) { sm += __shfl_down(sm, o); sq += __shfl_down(sq, o); }
        sm = __shfl(sm, 0); sq = __shfl(sq, 0);
        const float mean = sm * (1.0f / 192.0f);
        const float rstd = rsqrtf(sq * (1.0f / 192.0f) - mean * mean + 1e-5f);
        L.win[r][lane]       = f2bf((a0 - mean) * rstd * g1[lane]       + b1[lane]);
        L.win[r][lane + 64]  = f2bf((a1 - mean) * rstd * g1[lane + 64]  + b1[lane + 64]);
        L.win[r][lane + 128] = f2bf((a2 - mean) * rstd * g1[lane + 128] + b1[lane + 128]);
    }
    __syncthreads();

    // ---- Phase 2: per-head attention ----
    for (int h = 0; h < cNH; ++h) {
        const float* wqb = qkvw + (size_t)(h * cHD) * cC;
        const float* wkb = qkvw + (size_t)(cC + h * cHD) * cC;
        const float* wvb = qkvw + (size_t)(2 * cC + h * cHD) * cC;

        // qkv projection for this head: 49*32 outputs, 12 accumulator chains each
        for (int idx = tid; idx < cN * cHD; idx += NTHREADS) {
            const int n = idx >> 5, d = idx & 31;
            const float4* wq = (const float4*)(wqb + (size_t)d * cC);
            const float4* wk = (const float4*)(wkb + (size_t)d * cC);
            const float4* wv = (const float4*)(wvb + (size_t)d * cC);
            const uint2* wn = (const uint2*)L.win[n];
            float q0=0,q1=0,q2=0,q3=0,k0=0,k1=0,k2=0,k3=0,v0=0,v1=0,v2=0,v3=0;
            #pragma unroll 4
            for (int c4 = 0; c4 < cC / 4; ++c4) {
                const uint2 xw = wn[c4];
                const float x0 = bf2f((unsigned short)(xw.x)),  x1 = bf2f((unsigned short)(xw.x >> 16));
                const float x2 = bf2f((unsigned short)(xw.y)),  x3 = bf2f((unsigned short)(xw.y >> 16));
                const float4 aq = wq[c4]; q0 += x0*aq.x; q1 += x1*aq.y; q2 += x2*aq.z; q3 += x3*aq.w;
                const float4 ak = wk[c4]; k0 += x0*ak.x; k1 += x1*ak.y; k2 += x2*ak.z; k3 += x3*ak.w;
                const float4 av = wv[c4]; v0 += x0*av.x; v1 += x1*av.y; v2 += x2*av.z; v3 += x3*av.w;
            }
            L.q[n][d] = f2bf(((q0+q1)+(q2+q3) + qkvb[h*cHD + d]) * cSCALE);
            L.k[n][d] = f2bf((k0+k1)+(k2+k3) + qkvb[cC + h*cHD + d]);
            L.v[n][d] = f2bf((v0+v1)+(v2+v3) + qkvb[2*cC + h*cHD + d]);
        }
        __syncthreads();

        // scores + rel-pos bias + shift mask
        const float* mrow = mask + (size_t)wi * cN * cN;
        for (int idx = tid; idx < cN * cN; idx += NTHREADS) {
            const int n = idx / 49, m = idx - n * 49;
            const uint2* qp = (const uint2*)L.q[n];
            const uint2* kp = (const uint2*)L.k[m];
            float a0=0,a1=0,a2=0,a3=0;
            #pragma unroll
            for (int d4 = 0; d4 < 8; ++d4) {
                const uint2 qu = qp[d4], ku = kp[d4];
                a0 += bf2f((unsigned short)qu.x)         * bf2f((unsigned short)ku.x);
                a1 += bf2f((unsigned short)(qu.x >> 16)) * bf2f((unsigned short)(ku.x >> 16));
                a2 += bf2f((unsigned short)qu.y)         * bf2f((unsigned short)ku.y);
                a3 += bf2f((unsigned short)(qu.y >> 16)) * bf2f((unsigned short)(ku.y >> 16));
            }
            const int p1 = n / 7, q1i = n - p1 * 7, p2 = m / 7, q2i = m - p2 * 7;
            const int ridx = (p1 - p2 + 6) * 13 + (q1i - q2i + 6);
            L.s[n][m] = (a0 + a1) + (a2 + a3) + rpb[ridx * cNH + h] + mrow[idx];
        }
        __syncthreads();

        // softmax per query row
        for (int r = wave; r < cN; r += 4) {
            const float vsc = (lane < 49) ? L.s[r][lane] : -1e30f;
            float mx = vsc;
            #pragma unroll
            for (int o = 32; o > 0; o >>= 1) mx = fmaxf(mx, __shfl_down(mx, o));
            mx = __shfl(mx, 0);
            const float e = (lane < 49) ? __expf(vsc - mx) : 0.0f;
            float ssum = e;
            #pragma unroll
            for (int o = 32; o > 0; o >>= 1) ssum += __shfl_down(ssum, o);
            ssum = __shfl(ssum, 0);
            if (lane < 49) L.s[r][lane] = e / ssum;
        }
        __syncthreads();

        // PV
        for (int idx = tid; idx < cN * cHD; idx += NTHREADS) {
            const int n = idx >> 5, d = idx & 31;
            const float* sr = L.s[n];
            float a0=0,a1=0,a2=0,a3=0;
            #pragma unroll
            for (int m = 0; m < 48; m += 4) {
                a0 += sr[m]     * bf2f(L.v[m][d]);
                a1 += sr[m + 1] * bf2f(L.v[m + 1][d]);
                a2 += sr[m + 2] * bf2f(L.v[m + 2][d]);
                a3 += sr[m + 3] * bf2f(L.v[m + 3][d]);
            }
            a0 += sr[48] * bf2f(L.v[48][d]);
            L.po[n][h * cHD + d] = f2bf((a0 + a1) + (a2 + a3));
        }
        __syncthreads();   // protect q/k/v/s for next head
    }

    // ---- Phase 3: proj + residual, scatter back (window-reverse + unshift) ----
    for (int idx = tid; idx < cN * 48; idx += NTHREADS) {
        const int n = idx / 48, cg = (idx - n * 48) * 4;
        const uint2*  pr = (const uint2*)L.po[n];
        const float4* w0 = (const float4*)(pw + (size_t)(cg + 0) * cC);
        const float4* w1 = (const float4*)(pw + (size_t)(cg + 1) * cC);
        const float4* w2 = (const float4*)(pw + (size_t)(cg + 2) * cC);
        const float4* w3 = (const float4*)(pw + (size_t)(cg + 3) * cC);
        float a0=0,a1=0,a2=0,a3=0;
        #pragma unroll 4
        for (int c4 = 0; c4 < cC / 4; ++c4) {
            const uint2 pu = pr[c4];
            const float p0 = bf2f((unsigned short)pu.x),  p1v = bf2f((unsigned short)(pu.x >> 16));
            const float p2v = bf2f((unsigned short)pu.y), p3 = bf2f((unsigned short)(pu.y >> 16));
            const float4 u0 = w0[c4]; a0 += p0*u0.x + p1v*u0.y + p2v*u0.z + p3*u0.w;
            const float4 u1 = w1[c4]; a1 += p0*u1.x + p1v*u1.y + p2v*u1.z + p3*u1.w;
            const float4 u2 = w2[c4]; a2 += p0*u2.x + p1v*u2.y + p2v*u2.z + p3*u2.w;
            const float4 u3 = w3[c4]; a3 += p0*u3.x + p1v*u3.y + p2v*u3.z + p3*u3.w;
        }
        const int p = n / 7, q7 = n - p * 7;
        int i2 = wh * 7 + p + 3;  if (i2 >= 56) i2 -= 56;
        int j2 = ww * 7 + q7 + 3; if (j2 >= 56) j2 -= 56;
        const size_t base = ((size_t)(bb * 56 + i2) * 56 + j2) * cC + cg;
        y[base + 0] = x[base + 0] + pb[cg + 0] + a0;
        y[base + 1] = x[base + 1] + pb[cg + 1] + a1;
        y[base + 2] = x[base + 2] + pb[cg + 2] + a2;
        y[base + 3] = x[base + 3] + pb[cg + 3] + a3;
    }
}

// ---------------- Kernel B: LN2 + fc1 + GELU + fc2 + residual (in-place on y) ----------------
struct SB {
    unsigned short xn[16][cC];     // 6144 B
    unsigned short hbuf[16][768];  // 24576 B
};                                 // 30720 B

__global__ __launch_bounds__(NTHREADS)
void swin_mlp(const float* __restrict__ g2, const float* __restrict__ b2,
              const float* __restrict__ f1w, const float* __restrict__ f1b,
              const float* __restrict__ f2w, const float* __restrict__ f2b,
              float* __restrict__ y)
{
    __shared__ SB L;
    const int tid = threadIdx.x, lane = tid & 63, wave = tid >> 6;
    const size_t r0 = (size_t)blockIdx.x * 16;

    // LN2
    for (int r = wave; r < 16; r += 4) {
        const float* yr = y + (r0 + r) * cC;
        const float a0 = yr[lane], a1 = yr[lane + 64], a2 = yr[lane + 128];
        float sm = a0 + a1 + a2, sq = a0 * a0 + a1 * a1 + a2 * a2;
        #pragma unroll
        for (int o = 32; o > 0; o >>= 1) { sm += __shfl_down(sm, o); sq += __shfl_down(sq, o); }
        sm = __shfl(sm, 0); sq = __shfl(sq, 0);
        const float mean = sm * (1.0f / 192.0f);
        const float rstd = rsqrtf(sq * (1.0f / 192.0f) - mean * mean + 1e-5f);
        L.xn[r][lane]       = f2bf((a0 - mean) * rstd * g2[lane]       + b2[lane]);
        L.xn[r][lane + 64]  = f2bf((a1 - mean) * rstd * g2[lane + 64]  + b2[lane + 64]);
        L.xn[r][lane + 128] = f2bf((a2 - mean) * rstd * g2[lane + 128] + b2[lane + 128]);
    }
    __syncthreads();

    // fc1 + exact GELU: 16 rows x 768, 4 outputs per item
    for (int idx = tid; idx < 16 * 192; idx += NTHREADS) {
        const int r = idx / 192, dg = (idx - r * 192) * 4;
        const uint2*  xr = (const uint2*)L.xn[r];
        const float4* w0 = (const float4*)(f1w + (size_t)(dg + 0) * cC);
        const float4* w1 = (const float4*)(f1w + (size_t)(dg + 1) * cC);
        const float4* w2 = (const float4*)(f1w + (size_t)(dg + 2) * cC);
        const float4* w3 = (const float4*)(f1w + (size_t)(dg + 3) * cC);
        float a0=0,a1=0,a2=0,a3=0;
        #pragma unroll 4
        for (int c4 = 0; c4 < cC / 4; ++c4) {
            const uint2 xu = xr[c4];
            const float x0 = bf2f((unsigned short)xu.x),  x1 = bf2f((unsigned short)(xu.x >> 16));
            const float x2 = bf2f((unsigned short)xu.y),  x3 = bf2f((unsigned short)(xu.y >> 16));
            const float4 u0 = w0[c4]; a0 += x0*u0.x + x1*u0.y + x2*u0.z + x3*u0.w;
            const float4 u1 = w1[c4]; a1 += x0*u1.x + x1*u1.y + x2*u1.z + x3*u1.w;
            const float4 u2 = w2[c4]; a2 += x0*u2.x + x1*u2.y + x2*u2.z + x3*u2.w;
            const float4 u3 = w3[c4]; a3 += x0*u3.x + x1*u3.y + x2*u3.z + x3*u3.w;
        }
        const float t0 = a0 + f1b[dg + 0], t1 = a1 + f1b[dg + 1];
        const float t2 = a2 + f1b[dg + 2], t3 = a3 + f1b[dg + 3];
        L.hbuf[r][dg + 0] = f2bf(0.5f * t0 * (1.0f + erff(t0 * 0.70710678118654752f)));
        L.hbuf[r][dg + 1] = f2bf(0.5f * t1 * (1.0f + erff(t1 * 0.70710678118654752f)));
        L.hbuf[r][dg + 2] = f2bf(0.5f * t2 * (1.0f + erff(t2 * 0.70710678118654752f)));
        L.hbuf[r][dg + 3] = f2bf(0.5f * t3 * (1.0f + erff(t3 * 0.70710678118654752f)));
    }
    __syncthreads();

    // fc2 + residual (in-place)
    for (int idx = tid; idx < 16 * 48; idx += NTHREADS) {
        const int r = idx / 48, cg = (idx - r * 48) * 4;
        const uint2*  hr = (const uint2*)L.hbuf[r];
        const float4* w0 = (const float4*)(f2w + (size_t)(cg + 0) * 768);
        const float4* w1 = (const float4*)(f2w + (size_t)(cg + 1) * 768);
        const float4* w2 = (const float4*)(f2w + (size_t)(cg + 2) * 768);
        const float4* w3 = (const float4*)(f2w + (size_t)(cg + 3) * 768);
        float a0=0,a1=0,a2=0,a3=0;
        #pragma unroll 4
        for (int d4 = 0; d4 < 192; ++d4) {
            const uint2 hu = hr[d4];
            const float h0 = bf2f((unsigned short)hu.x),  h1 = bf2f((unsigned short)(hu.x >> 16));
            const float h2 = bf2f((unsigned short)hu.y),  h3 = bf2f((unsigned short)(hu.y >> 16));
            const float4 u0 = w0[d4]; a0 += h0*u0.x + h1*u0.y + h2*u0.z + h3*u0.w;
            const float4 u1 = w1[d4]; a1 += h0*u1.x + h1*u1.y + h2*u1.z + h3*u1.w;
            const float4 u2 = w2[d4]; a2 += h0*u2.x + h1*u2.y + h2*u2.z + h3*u2.w;
            const float4 u3 = w3[d4]; a3 += h0*u3.x + h1*u3.y + h2*u3.z + h3*u3.w;
        }
        float* yp = y + (r0 + r) * cC + cg;
        yp[0] = yp[0] + f2b[cg + 0] + a0;
        yp[1] = yp[1] + f2b[cg + 1] + a1;
        yp[2] = yp[2] + f2b[cg + 2] + a2;
        yp[3] = yp[3] + f2b[cg + 3] + a3;
    }
}

extern "C" void kernel_launch(void* const* d_in, const int* in_sizes, int n_in,
                              void* d_out, int out_size, void* d_ws, size_t ws_size,
                              hipStream_t stream) {
    (void)in_sizes; (void)n_in; (void)d_ws; (void)ws_size; (void)out_size;
    const float* x    = (const float*)d_in[0];
    const float* mask = (const float*)d_in[1];
    const float* g1   = (const float*)d_in[2];
    const float* b1   = (const float*)d_in[3];
    const float* qkvw = (const float*)d_in[4];
    const float* qkvb = (const float*)d_in[5];
    const float* rpb  = (const float*)d_in[6];
    const float* pw   = (const float*)d_in[7];
    const float* pb   = (const float*)d_in[8];
    const float* g2   = (const float*)d_in[9];
    const float* b2   = (const float*)d_in[10];
    const float* f1w  = (const float*)d_in[11];
    const float* f1b  = (const float*)d_in[12];
    const float* f2w  = (const float*)d_in[13];
    const float* f2b  = (const float*)d_in[14];
    float* y = (float*)d_out;

    swin_attn<<<dim3(64 * 64), dim3(NTHREADS), 0, stream>>>(
        x, mask, g1, b1, qkvw, qkvb, rpb, pw, pb, y);
    swin_mlp<<<dim3((64 * 56 * 56) / 16), dim3(NTHREADS), 0, stream>>>(
        g2, b2, f1w, f1b, f2w, f2b, y);
}

// Round 2
// 2249.834 us; speedup vs baseline: 20.1818x; 20.1818x over previous
//
#include <hip/hip_runtime.h>
#include <hip/hip_bf16.h>
#include <math.h>

typedef __attribute__((ext_vector_type(8))) short s16x8;
typedef __attribute__((ext_vector_type(4))) float f32x4;

static constexpr float cSCALE = 0.17677669529663687f; // 32^-0.5

__device__ __forceinline__ float bf2f(unsigned short u) {
    union { unsigned int i; float f; } c; c.i = ((unsigned int)u) << 16; return c.f;
}
__device__ __forceinline__ unsigned short f2bf(float f) {
    union { float f; unsigned int i; } c; c.f = f;
    unsigned int r = c.i + (0x7fffu + ((c.i >> 16) & 1u));
    return (unsigned short)(r >> 16);
}
__device__ __forceinline__ s16x8 cvt8(const float4 a, const float4 b) {
    s16x8 r;
    r[0]=(short)f2bf(a.x); r[1]=(short)f2bf(a.y); r[2]=(short)f2bf(a.z); r[3]=(short)f2bf(a.w);
    r[4]=(short)f2bf(b.x); r[5]=(short)f2bf(b.y); r[6]=(short)f2bf(b.z); r[7]=(short)f2bf(b.w);
    return r;
}

// =================== Kernel A: LN1 + shift/window + MFMA attention + proj + residual ===================
__global__ __launch_bounds__(256)
void swin_attn(const float* __restrict__ x, const float* __restrict__ mask,
               const float* __restrict__ g1, const float* __restrict__ b1,
               const float* __restrict__ qkvw, const float* __restrict__ qkvb,
               const float* __restrict__ rpb, const float* __restrict__ pw,
               const float* __restrict__ pb, float* __restrict__ y)
{
    __shared__ __align__(16) unsigned short win_[64][200]; // 25600 B (LN'd shifted window, bf16)
    __shared__ __align__(16) unsigned short q_[64][40];    // 5120
    __shared__ __align__(16) unsigned short k_[64][40];    // 5120
    __shared__ __align__(16) unsigned short vt_[32][72];   // 4608 (V transposed: [d][token])
    __shared__ __align__(16) unsigned short p_[64][72];    // 9216 (softmax probs bf16)
    __shared__ __align__(16) unsigned short oh_[64][40];   // 5120 (per-head attn out)
    __shared__ __align__(16) unsigned short mk_[49*52];    // 5096 (shift mask bf16)
    __shared__ __align__(16) float          rp_[1014];     // 4056 (rpb table fp32)
    // total 63936 B

    const int w  = blockIdx.x;
    const int bb = w >> 6, wi = w & 63;
    const int wh = wi >> 3, ww = wi & 7;
    const int tid = threadIdx.x, lane = tid & 63, wave = tid >> 6;
    const int ln = lane & 15, ko = (lane >> 4) * 8, ro = (lane >> 4) * 4;
    const int m0 = wave * 16;

    // ---- Phase 1: LN1 + shifted gather (rows 49-63 zeroed) + stage mask/rpb ----
    for (int r = wave; r < 64; r += 4) {
        if (r < 49) {
            const int p = r / 7, q7 = r - p * 7;
            int i2 = wh * 7 + p + 3;  if (i2 >= 56) i2 -= 56;
            int j2 = ww * 7 + q7 + 3; if (j2 >= 56) j2 -= 56;
            const float* xr = x + ((size_t)(bb * 56 + i2) * 56 + j2) * 192;
            const float a0 = xr[lane], a1 = xr[lane + 64], a2 = xr[lane + 128];
            float sm = a0 + a1 + a2, sq = a0*a0 + a1*a1 + a2*a2;
            #pragma unroll
            for (int o = 32; o > 0; o >>= 1) { sm += __shfl_down(sm, o); sq += __shfl_down(sq, o); }
            sm = __shfl(sm, 0); sq = __shfl(sq, 0);
            const float mean = sm * (1.0f / 192.0f);
            const float rstd = rsqrtf(sq * (1.0f / 192.0f) - mean * mean + 1e-5f);
            win_[r][lane]       = f2bf((a0 - mean) * rstd * g1[lane]       + b1[lane]);
            win_[r][lane + 64]  = f2bf((a1 - mean) * rstd * g1[lane + 64]  + b1[lane + 64]);
            win_[r][lane + 128] = f2bf((a2 - mean) * rstd * g1[lane + 128] + b1[lane + 128]);
        } else {
            win_[r][lane] = 0; win_[r][lane + 64] = 0; win_[r][lane + 128] = 0;
        }
    }
    for (int t = tid; t < 2401; t += 256) {
        const int n = t / 49, m = t - n * 49;
        mk_[n * 52 + m] = f2bf(mask[(size_t)wi * 2401 + t]);
    }
    for (int t = tid; t < 1014; t += 256) rp_[t] = rpb[t];
    __syncthreads();

    f32x4 accp[12];
    #pragma unroll
    for (int i = 0; i < 12; ++i) accp[i] = f32x4{0.f,0.f,0.f,0.f};

    for (int h = 0; h < 6; ++h) {
        // ---- QKV: [64x96] = win[64x192] @ B, cols = [Qh(32) | Kh(32) | Vh(32)] ----
        f32x4 acc[6];
        #pragma unroll
        for (int i = 0; i < 6; ++i) acc[i] = f32x4{0.f,0.f,0.f,0.f};
        #pragma unroll
        for (int kf = 0; kf < 6; ++kf) {
            const s16x8 a = *(const s16x8*)&win_[m0 + ln][kf * 32 + ko];
            #pragma unroll
            for (int nf = 0; nf < 6; ++nf) {
                const float* src = qkvw + ((size_t)((nf >> 1) * 192 + h * 32 + (nf & 1) * 16 + ln)) * 192
                                 + kf * 32 + ko;
                const s16x8 b = cvt8(*(const float4*)src, *(const float4*)(src + 4));
                acc[nf] = __builtin_amdgcn_mfma_f32_16x16x32_bf16(a, b, acc[nf], 0, 0, 0);
            }
        }
        #pragma unroll
        for (int nf = 0; nf < 6; ++nf) {
            const int col = nf * 16 + ln;
            #pragma unroll
            for (int i = 0; i < 4; ++i) {
                const int row = m0 + ro + i;
                const float v = acc[nf][i];
                if (nf < 2)      q_[row][col]      = f2bf((v + qkvb[h*32 + col]) * cSCALE);
                else if (nf < 4) k_[row][col - 32] = f2bf(v + qkvb[192 + h*32 + col - 32]);
                else             vt_[col - 64][row] = f2bf(v + qkvb[384 + h*32 + col - 64]);
            }
        }
        __syncthreads();

        // ---- S = Q @ K^T  [64x64], + bias + mask, softmax -> p_ ----
        f32x4 s[4];
        {
            const s16x8 aq = *(const s16x8*)&q_[m0 + ln][ko];
            #pragma unroll
            for (int nf = 0; nf < 4; ++nf) {
                const s16x8 bk = *(const s16x8*)&k_[nf * 16 + ln][ko];
                s[nf] = __builtin_amdgcn_mfma_f32_16x16x32_bf16(aq, bk, f32x4{0.f,0.f,0.f,0.f}, 0, 0, 0);
            }
        }
        #pragma unroll
        for (int i = 0; i < 4; ++i) {
            const int n = m0 + ro + i;
            float v[4];
            #pragma unroll
            for (int nf = 0; nf < 4; ++nf) {
                const int m = nf * 16 + ln;
                float t = s[nf][i];
                if (m >= 49) t = -1e30f;
                else if (n < 49) {
                    const int p1 = n / 7, q1 = n - p1 * 7, p2 = m / 7, q2 = m - p2 * 7;
                    const int ridx = (p1 - p2 + 6) * 13 + (q1 - q2 + 6);
                    t += rp_[ridx * 6 + h] + bf2f(mk_[n * 52 + m]);
                }
                v[nf] = t;
            }
            float mx = fmaxf(fmaxf(v[0], v[1]), fmaxf(v[2], v[3]));
            #pragma unroll
            for (int o = 1; o < 16; o <<= 1) mx = fmaxf(mx, __shfl_xor(mx, o));
            float e[4], ssum = 0.f;
            #pragma unroll
            for (int nf = 0; nf < 4; ++nf) { e[nf] = __expf(v[nf] - mx); ssum += e[nf]; }
            #pragma unroll
            for (int o = 1; o < 16; o <<= 1) ssum += __shfl_xor(ssum, o);
            const float inv = 1.0f / ssum;
            #pragma unroll
            for (int nf = 0; nf < 4; ++nf) p_[n][nf * 16 + ln] = f2bf(e[nf] * inv);
        }
        __syncthreads();

        // ---- O = P @ V  [64x32] ----
        f32x4 o[2];
        #pragma unroll
        for (int i = 0; i < 2; ++i) o[i] = f32x4{0.f,0.f,0.f,0.f};
        #pragma unroll
        for (int kf = 0; kf < 2; ++kf) {
            const s16x8 ap = *(const s16x8*)&p_[m0 + ln][kf * 32 + ko];
            #pragma unroll
            for (int nf = 0; nf < 2; ++nf) {
                const s16x8 bv = *(const s16x8*)&vt_[nf * 16 + ln][kf * 32 + ko];
                o[nf] = __builtin_amdgcn_mfma_f32_16x16x32_bf16(ap, bv, o[nf], 0, 0, 0);
            }
        }
        #pragma unroll
        for (int nf = 0; nf < 2; ++nf)
            #pragma unroll
            for (int i = 0; i < 4; ++i)
                oh_[m0 + ro + i][nf * 16 + ln] = f2bf(o[nf][i]);
        __syncthreads();

        // ---- proj partial: out += O_h @ pw[:, h*32:(h+1)*32]^T ----
        {
            const s16x8 ao = *(const s16x8*)&oh_[m0 + ln][ko];
            #pragma unroll
            for (int nf = 0; nf < 12; ++nf) {
                const float* src = pw + (size_t)(nf * 16 + ln) * 192 + h * 32 + ko;
                const s16x8 b = cvt8(*(const float4*)src, *(const float4*)(src + 4));
                accp[nf] = __builtin_amdgcn_mfma_f32_16x16x32_bf16(ao, b, accp[nf], 0, 0, 0);
            }
        }
        __syncthreads();
    }

    // ---- Epilogue: + proj bias + residual, scatter to shifted coords ----
    #pragma unroll
    for (int i = 0; i < 4; ++i) {
        const int n = m0 + ro + i;
        if (n < 49) {
            const int p = n / 7, q7 = n - p * 7;
            int i2 = wh * 7 + p + 3;  if (i2 >= 56) i2 -= 56;
            int j2 = ww * 7 + q7 + 3; if (j2 >= 56) j2 -= 56;
            const size_t base = ((size_t)(bb * 56 + i2) * 56 + j2) * 192;
            #pragma unroll
            for (int nf = 0; nf < 12; ++nf) {
                const int col = nf * 16 + ln;
                y[base + col] = x[base + col] + pb[col] + accp[nf][i];
            }
        }
    }
}

// =================== Kernel B: LN2 + fc1 + GELU + fc2 + residual (MFMA, in-place) ===================
__global__ __launch_bounds__(256)
void swin_mlp(const float* __restrict__ g2, const float* __restrict__ b2,
              const float* __restrict__ f1w, const float* __restrict__ f1b,
              const float* __restrict__ f2w, const float* __restrict__ f2b,
              float* __restrict__ y)
{
    __shared__ __align__(16) unsigned short xn[64][200];  // 25600 B
    __shared__ __align__(16) unsigned short hb[64][72];   // 9216 B
    __shared__ __align__(16) unsigned short Bst[13824];   // 27648 B (union: B1 [64][200] / B2 [192][72])
    // total 62464 B

    const int tid = threadIdx.x, lane = tid & 63, wave = tid >> 6;
    const int ln = lane & 15, ko = (lane >> 4) * 8, ro = (lane >> 4) * 4;
    const int m0 = wave * 16;
    const size_t r0 = (size_t)blockIdx.x * 64;

    // ---- LN2 -> xn (bf16) ----
    for (int r = wave; r < 64; r += 4) {
        const float* yr = y + (r0 + r) * 192;
        const float a0 = yr[lane], a1 = yr[lane + 64], a2 = yr[lane + 128];
        float sm = a0 + a1 + a2, sq = a0*a0 + a1*a1 + a2*a2;
        #pragma unroll
        for (int o = 32; o > 0; o >>= 1) { sm += __shfl_down(sm, o); sq += __shfl_down(sq, o); }
        sm = __shfl(sm, 0); sq = __shfl(sq, 0);
        const float mean = sm * (1.0f / 192.0f);
        const float rstd = rsqrtf(sq * (1.0f / 192.0f) - mean * mean + 1e-5f);
        xn[r][lane]       = f2bf((a0 - mean) * rstd * g2[lane]       + b2[lane]);
        xn[r][lane + 64]  = f2bf((a1 - mean) * rstd * g2[lane + 64]  + b2[lane + 64]);
        xn[r][lane + 128] = f2bf((a2 - mean) * rstd * g2[lane + 128] + b2[lane + 128]);
    }
    __syncthreads();

    f32x4 acc2[12];
    #pragma unroll
    for (int i = 0; i < 12; ++i) acc2[i] = f32x4{0.f,0.f,0.f,0.f};

    for (int nb = 0; nb < 12; ++nb) {
        // ---- stage B1 = f1w[nb*64 .. +64][0..192] -> bf16 LDS [64][200] ----
        for (int t = tid; t < 3072; t += 256) {
            const int n = t / 48, k4 = t - n * 48;
            const float4 wv = *(const float4*)(f1w + ((size_t)(nb * 64 + n)) * 192 + k4 * 4);
            unsigned short* dst = &Bst[n * 200 + k4 * 4];
            dst[0] = f2bf(wv.x); dst[1] = f2bf(wv.y); dst[2] = f2bf(wv.z); dst[3] = f2bf(wv.w);
        }
        __syncthreads();

        // ---- GEMM1: h_chunk[64x64] = xn @ B1^T ----
        f32x4 acc1[4];
        #pragma unroll
        for (int i = 0; i < 4; ++i) acc1[i] = f32x4{0.f,0.f,0.f,0.f};
        #pragma unroll
        for (int kf = 0; kf < 6; ++kf) {
            const s16x8 a = *(const s16x8*)&xn[m0 + ln][kf * 32 + ko];
            #pragma unroll
            for (int nf = 0; nf < 4; ++nf) {
                const s16x8 b = *(const s16x8*)&Bst[(nf * 16 + ln) * 200 + kf * 32 + ko];
                acc1[nf] = __builtin_amdgcn_mfma_f32_16x16x32_bf16(a, b, acc1[nf], 0, 0, 0);
            }
        }
        // GELU + bias -> hb
        #pragma unroll
        for (int nf = 0; nf < 4; ++nf) {
            const int col = nf * 16 + ln;
            const float bias = f1b[nb * 64 + col];
            #pragma unroll
            for (int i = 0; i < 4; ++i) {
                const float t = acc1[nf][i] + bias;
                hb[m0 + ro + i][col] = f2bf(0.5f * t * (1.0f + erff(t * 0.70710678118654752f)));
            }
        }
        __syncthreads();   // B1 reads done, hb written

        // ---- stage B2 = f2w[0..192][nb*64 .. +64] -> bf16 LDS [192][72] ----
        for (int t = tid; t < 3072; t += 256) {
            const int c = t >> 4, k4 = t & 15;
            const float4 wv = *(const float4*)(f2w + (size_t)c * 768 + nb * 64 + k4 * 4);
            unsigned short* dst = &Bst[c * 72 + k4 * 4];
            dst[0] = f2bf(wv.x); dst[1] = f2bf(wv.y); dst[2] = f2bf(wv.z); dst[3] = f2bf(wv.w);
        }
        __syncthreads();

        // ---- GEMM2: out += h_chunk @ B2^T ----
        #pragma unroll
        for (int kf = 0; kf < 2; ++kf) {
            const s16x8 a = *(const s16x8*)&hb[m0 + ln][kf * 32 + ko];
            #pragma unroll
            for (int nf = 0; nf < 12; ++nf) {
                const s16x8 b = *(const s16x8*)&Bst[(nf * 16 + ln) * 72 + kf * 32 + ko];
                acc2[nf] = __builtin_amdgcn_mfma_f32_16x16x32_bf16(a, b, acc2[nf], 0, 0, 0);
            }
        }
        __syncthreads();   // B2/hb reads done before next chunk overwrites
    }

    // ---- Epilogue: + fc2 bias + residual (in-place) ----
    #pragma unroll
    for (int i = 0; i < 4; ++i) {
        const int row = m0 + ro + i;
        float* yp = y + (r0 + row) * 192;
        #pragma unroll
        for (int nf = 0; nf < 12; ++nf) {
            const int col = nf * 16 + ln;
            yp[col] = yp[col] + f2b[col] + acc2[nf][i];
        }
    }
}

extern "C" void kernel_launch(void* const* d_in, const int* in_sizes, int n_in,
                              void* d_out, int out_size, void* d_ws, size_t ws_size,
                              hipStream_t stream) {
    (void)in_sizes; (void)n_in; (void)d_ws; (void)ws_size; (void)out_size;
    const float* x    = (const float*)d_in[0];
    const float* mask = (const float*)d_in[1];
    const float* g1   = (const float*)d_in[2];
    const float* b1   = (const float*)d_in[3];
    const float* qkvw = (const float*)d_in[4];
    const float* qkvb = (const float*)d_in[5];
    const float* rpb  = (const float*)d_in[6];
    const float* pw   = (const float*)d_in[7];
    const float* pb   = (const float*)d_in[8];
    const float* g2   = (const float*)d_in[9];
    const float* b2   = (const float*)d_in[10];
    const float* f1w  = (const float*)d_in[11];
    const float* f1b  = (const float*)d_in[12];
    const float* f2w  = (const float*)d_in[13];
    const float* f2b  = (const float*)d_in[14];
    float* y = (float*)d_out;

    swin_attn<<<dim3(64 * 64), dim3(256), 0, stream>>>(
        x, mask, g1, b1, qkvw, qkvb, rpb, pw, pb, y);
    swin_mlp<<<dim3(3136), dim3(256), 0, stream>>>(
        g2, b2, f1w, f1b, f2w, f2b, y);
}

// Round 3
// 1706.369 us; speedup vs baseline: 26.6096x; 1.3185x over previous
//
#include <hip/hip_runtime.h>
#include <hip/hip_bf16.h>
#include <math.h>

typedef __attribute__((ext_vector_type(8))) short s16x8;
typedef __attribute__((ext_vector_type(4))) float f32x4;

static constexpr float cSCALE = 0.17677669529663687f; // 32^-0.5

__device__ __forceinline__ float bf2f(unsigned short u) {
    union { unsigned int i; float f; } c; c.i = ((unsigned int)u) << 16; return c.f;
}
__device__ __forceinline__ unsigned short f2bf(float f) {
    union { float f; unsigned int i; } c; c.f = f;
    unsigned int r = c.i + (0x7fffu + ((c.i >> 16) & 1u));
    return (unsigned short)(r >> 16);
}
__device__ __forceinline__ s16x8 cvt8(const float4 a, const float4 b) {
    s16x8 r;
    r[0]=(short)f2bf(a.x); r[1]=(short)f2bf(a.y); r[2]=(short)f2bf(a.z); r[3]=(short)f2bf(a.w);
    r[4]=(short)f2bf(b.x); r[5]=(short)f2bf(b.y); r[6]=(short)f2bf(b.z); r[7]=(short)f2bf(b.w);
    return r;
}
__device__ __forceinline__ float gelu_f(float t) {
    // 0.5*t*(1+tanh(0.79788456*(t+0.044715*t^3))) == t*sigmoid(1.59576912*t*(1+0.044715*t^2))
    const float u = 1.5957691216057308f * t * (1.0f + 0.044715f * t * t);
    return t / (1.0f + __expf(-u));
}

// ============ Prep: pack weights to bf16 MFMA-fragment layout in d_ws ============
// fragment fid: [0,216)   qkv  : fid = h*36 + nf*6 + kf
//              [216,288)  proj : fid = 216 + h*12 + nf
//              [288,576)  fc1  : fid = 288 + nb*24 + nf*6 + kf
//              [576,864)  fc2  : fid = 576 + nb*24 + nf*2 + kf
// element: ws[fid*512 + lane*8 + j] = W[row(lane)][k0 + (lane>>4)*8 + j]
__global__ __launch_bounds__(256)
void pack_w(const float* __restrict__ qkvw, const float* __restrict__ pw,
            const float* __restrict__ f1w, const float* __restrict__ f2w,
            unsigned short* __restrict__ o)
{
    const int t = blockIdx.x * 256 + threadIdx.x; // 0..55295
    const int lane = t & 63, f = t >> 6;
    const int ln = lane & 15, ko = (lane >> 4) * 8;
    const float* src;
    if (f < 216) {
        const int h = f / 36, r = f - h * 36, nf = r / 6, kf = r - nf * 6;
        src = qkvw + (size_t)((nf >> 1) * 192 + h * 32 + (nf & 1) * 16 + ln) * 192 + kf * 32 + ko;
    } else if (f < 288) {
        const int g = f - 216, h = g / 12, nf = g - h * 12;
        src = pw + (size_t)(nf * 16 + ln) * 192 + h * 32 + ko;
    } else if (f < 576) {
        const int g = f - 288, nb = g / 24, r = g - nb * 24, nf = r / 6, kf = r - nf * 6;
        src = f1w + (size_t)(nb * 64 + nf * 16 + ln) * 192 + kf * 32 + ko;
    } else {
        const int g = f - 576, nb = g / 24, r = g - nb * 24, nf = r >> 1, kf = r & 1;
        src = f2w + (size_t)(nf * 16 + ln) * 768 + nb * 64 + kf * 32 + ko;
    }
    *(s16x8*)(o + (size_t)t * 8) = cvt8(*(const float4*)src, *(const float4*)(src + 4));
}

// ============ Kernel A: LN1 + shift/window + MFMA attention + proj + residual ============
__global__ __launch_bounds__(256)
void swin_attn(const float* __restrict__ x, const float* __restrict__ mask,
               const float* __restrict__ g1, const float* __restrict__ b1,
               const unsigned short* __restrict__ wp, const float* __restrict__ qkvb,
               const float* __restrict__ rpb, const float* __restrict__ pb,
               float* __restrict__ y)
{
    __shared__ __align__(16) unsigned short win_[64][200]; // 25600 B
    __shared__ __align__(16) unsigned short qo_[64][40];   // 5120 (union: Q then attn-out; wave-private)
    __shared__ __align__(16) unsigned short k_[64][40];    // 5120
    __shared__ __align__(16) unsigned short vt_[32][72];   // 4608 (V^T [d][token])
    __shared__ __align__(16) unsigned short p_[64][72];    // 9216 (probs; rows wave-private)
    __shared__ __align__(16) unsigned short rp_[1016];     // 2032 (rpb bf16)
    // total 51696 B -> 3 blocks/CU

    const s16x8* wv = (const s16x8*)wp;
    const int w  = blockIdx.x;
    const int bb = w >> 6, wi = w & 63;
    const int wh = wi >> 3, ww = wi & 7;
    const int tid = threadIdx.x, lane = tid & 63, wave = tid >> 6;
    const int ln = lane & 15, ko = (lane >> 4) * 8, ro = (lane >> 4) * 4;
    const int m0 = wave * 16;

    // ---- LN1 + shifted gather (rows 49-63 zeroed) ----
    for (int r = wave; r < 64; r += 4) {
        if (r < 49) {
            const int p = r / 7, q7 = r - p * 7;
            int i2 = wh * 7 + p + 3;  if (i2 >= 56) i2 -= 56;
            int j2 = ww * 7 + q7 + 3; if (j2 >= 56) j2 -= 56;
            const float* xr = x + ((size_t)(bb * 56 + i2) * 56 + j2) * 192;
            const float a0 = xr[lane], a1 = xr[lane + 64], a2 = xr[lane + 128];
            float sm = a0 + a1 + a2, sq = a0*a0 + a1*a1 + a2*a2;
            #pragma unroll
            for (int o = 32; o > 0; o >>= 1) { sm += __shfl_down(sm, o); sq += __shfl_down(sq, o); }
            sm = __shfl(sm, 0); sq = __shfl(sq, 0);
            const float mean = sm * (1.0f / 192.0f);
            const float rstd = rsqrtf(sq * (1.0f / 192.0f) - mean * mean + 1e-5f);
            win_[r][lane]       = f2bf((a0 - mean) * rstd * g1[lane]       + b1[lane]);
            win_[r][lane + 64]  = f2bf((a1 - mean) * rstd * g1[lane + 64]  + b1[lane + 64]);
            win_[r][lane + 128] = f2bf((a2 - mean) * rstd * g1[lane + 128] + b1[lane + 128]);
        } else {
            win_[r][lane] = 0; win_[r][lane + 64] = 0; win_[r][lane + 128] = 0;
        }
    }
    for (int t = tid; t < 1014; t += 256) rp_[t] = f2bf(rpb[t]);
    __syncthreads();

    f32x4 accp[12];
    #pragma unroll
    for (int i = 0; i < 12; ++i) accp[i] = f32x4{0.f,0.f,0.f,0.f};

    for (int h = 0; h < 6; ++h) {
        // ---- QKV: [64x96] ----
        f32x4 acc[6];
        #pragma unroll
        for (int i = 0; i < 6; ++i) acc[i] = f32x4{0.f,0.f,0.f,0.f};
        #pragma unroll
        for (int kf = 0; kf < 6; ++kf) {
            const s16x8 a = *(const s16x8*)&win_[m0 + ln][kf * 32 + ko];
            #pragma unroll
            for (int nf = 0; nf < 6; ++nf)
                acc[nf] = __builtin_amdgcn_mfma_f32_16x16x32_bf16(
                    a, wv[((h * 36 + nf * 6 + kf) << 6) + lane], acc[nf], 0, 0, 0);
        }
        #pragma unroll
        for (int nf = 0; nf < 6; ++nf) {
            const int col = nf * 16 + ln;
            #pragma unroll
            for (int i = 0; i < 4; ++i) {
                const int row = m0 + ro + i;
                const float v = acc[nf][i];
                if (nf < 2)      qo_[row][col]       = f2bf((v + qkvb[h*32 + col]) * cSCALE);
                else if (nf < 4) k_[row][col - 32]   = f2bf(v + qkvb[192 + h*32 + col - 32]);
                else             vt_[col - 64][row]  = f2bf(v + qkvb[384 + h*32 + col - 64]);
            }
        }
        __syncthreads();   // k_/vt_ cross-wave

        // ---- S = Q @ K^T + bias + mask, softmax -> p_ (rows wave-private) ----
        f32x4 s[4];
        {
            const s16x8 aq = *(const s16x8*)&qo_[m0 + ln][ko];
            #pragma unroll
            for (int nf = 0; nf < 4; ++nf) {
                const s16x8 bk = *(const s16x8*)&k_[nf * 16 + ln][ko];
                s[nf] = __builtin_amdgcn_mfma_f32_16x16x32_bf16(aq, bk, f32x4{0.f,0.f,0.f,0.f}, 0, 0, 0);
            }
        }
        const float* mrow = mask + (size_t)wi * 2401;
        #pragma unroll
        for (int i = 0; i < 4; ++i) {
            const int n = m0 + ro + i;
            float v[4];
            #pragma unroll
            for (int nf = 0; nf < 4; ++nf) {
                const int m = nf * 16 + ln;
                float t = s[nf][i];
                if (m >= 49) t = -1e30f;
                else if (n < 49) {
                    const int p1 = n / 7, q1 = n - p1 * 7, p2 = m / 7, q2 = m - p2 * 7;
                    const int ridx = (p1 - p2 + 6) * 13 + (q1 - q2 + 6);
                    t += bf2f(rp_[ridx * 6 + h]) + mrow[n * 49 + m];
                }
                v[nf] = t;
            }
            float mx = fmaxf(fmaxf(v[0], v[1]), fmaxf(v[2], v[3]));
            #pragma unroll
            for (int o = 1; o < 16; o <<= 1) mx = fmaxf(mx, __shfl_xor(mx, o));
            float e[4], ssum = 0.f;
            #pragma unroll
            for (int nf = 0; nf < 4; ++nf) { e[nf] = __expf(v[nf] - mx); ssum += e[nf]; }
            #pragma unroll
            for (int o = 1; o < 16; o <<= 1) ssum += __shfl_xor(ssum, o);
            const float inv = 1.0f / ssum;
            #pragma unroll
            for (int nf = 0; nf < 4; ++nf) p_[n][nf * 16 + ln] = f2bf(e[nf] * inv);
        }
        // no barrier: p_ rows wave-private, vt_ already synced

        // ---- O = P @ V [64x32] -> qo_ (wave-private) ----
        f32x4 o[2];
        #pragma unroll
        for (int i = 0; i < 2; ++i) o[i] = f32x4{0.f,0.f,0.f,0.f};
        #pragma unroll
        for (int kf = 0; kf < 2; ++kf) {
            const s16x8 ap = *(const s16x8*)&p_[m0 + ln][kf * 32 + ko];
            #pragma unroll
            for (int nf = 0; nf < 2; ++nf) {
                const s16x8 bv = *(const s16x8*)&vt_[nf * 16 + ln][kf * 32 + ko];
                o[nf] = __builtin_amdgcn_mfma_f32_16x16x32_bf16(ap, bv, o[nf], 0, 0, 0);
            }
        }
        #pragma unroll
        for (int nf = 0; nf < 2; ++nf)
            #pragma unroll
            for (int i = 0; i < 4; ++i)
                qo_[m0 + ro + i][nf * 16 + ln] = f2bf(o[nf][i]);

        // ---- proj partial (A wave-private) ----
        {
            const s16x8 ao = *(const s16x8*)&qo_[m0 + ln][ko];
            #pragma unroll
            for (int nf = 0; nf < 12; ++nf)
                accp[nf] = __builtin_amdgcn_mfma_f32_16x16x32_bf16(
                    ao, wv[((216 + h * 12 + nf) << 6) + lane], accp[nf], 0, 0, 0);
        }
        __syncthreads();   // protect k_/vt_/p_ before next head overwrites
    }

    // ---- Epilogue: + proj bias + residual, scatter to shifted coords ----
    #pragma unroll
    for (int i = 0; i < 4; ++i) {
        const int n = m0 + ro + i;
        if (n < 49) {
            const int p = n / 7, q7 = n - p * 7;
            int i2 = wh * 7 + p + 3;  if (i2 >= 56) i2 -= 56;
            int j2 = ww * 7 + q7 + 3; if (j2 >= 56) j2 -= 56;
            const size_t base = ((size_t)(bb * 56 + i2) * 56 + j2) * 192;
            #pragma unroll
            for (int nf = 0; nf < 12; ++nf) {
                const int col = nf * 16 + ln;
                y[base + col] = x[base + col] + pb[col] + accp[nf][i];
            }
        }
    }
}

// ============ Kernel B: LN2 + fc1 + GELU + fc2 + residual (MFMA, in-place) ============
__global__ __launch_bounds__(256)
void swin_mlp(const float* __restrict__ g2, const float* __restrict__ b2,
              const unsigned short* __restrict__ wp,
              const float* __restrict__ f1b, const float* __restrict__ f2b,
              float* __restrict__ y)
{
    __shared__ __align__(16) unsigned short xn[64][200];  // 25600 B
    __shared__ __align__(16) unsigned short hb[64][72];   // 9216 B (rows wave-private)
    // total 34816 B -> 4 blocks/CU

    const s16x8* wv = (const s16x8*)wp;
    const int tid = threadIdx.x, lane = tid & 63, wave = tid >> 6;
    const int ln = lane & 15, ko = (lane >> 4) * 8, ro = (lane >> 4) * 4;
    const int m0 = wave * 16;
    const size_t r0 = (size_t)blockIdx.x * 64;

    // ---- LN2 -> xn (bf16) ----
    for (int r = wave; r < 64; r += 4) {
        const float* yr = y + (r0 + r) * 192;
        const float a0 = yr[lane], a1 = yr[lane + 64], a2 = yr[lane + 128];
        float sm = a0 + a1 + a2, sq = a0*a0 + a1*a1 + a2*a2;
        #pragma unroll
        for (int o = 32; o > 0; o >>= 1) { sm += __shfl_down(sm, o); sq += __shfl_down(sq, o); }
        sm = __shfl(sm, 0); sq = __shfl(sq, 0);
        const float mean = sm * (1.0f / 192.0f);
        const float rstd = rsqrtf(sq * (1.0f / 192.0f) - mean * mean + 1e-5f);
        xn[r][lane]       = f2bf((a0 - mean) * rstd * g2[lane]       + b2[lane]);
        xn[r][lane + 64]  = f2bf((a1 - mean) * rstd * g2[lane + 64]  + b2[lane + 64]);
        xn[r][lane + 128] = f2bf((a2 - mean) * rstd * g2[lane + 128] + b2[lane + 128]);
    }
    __syncthreads();

    f32x4 acc2[12];
    #pragma unroll
    for (int i = 0; i < 12; ++i) acc2[i] = f32x4{0.f,0.f,0.f,0.f};

    for (int nb = 0; nb < 12; ++nb) {
        // ---- GEMM1: h_chunk[64x64] = xn @ f1w_chunk^T ----
        f32x4 acc1[4];
        #pragma unroll
        for (int i = 0; i < 4; ++i) acc1[i] = f32x4{0.f,0.f,0.f,0.f};
        #pragma unroll
        for (int kf = 0; kf < 6; ++kf) {
            const s16x8 a = *(const s16x8*)&xn[m0 + ln][kf * 32 + ko];
            #pragma unroll
            for (int nf = 0; nf < 4; ++nf)
                acc1[nf] = __builtin_amdgcn_mfma_f32_16x16x32_bf16(
                    a, wv[((288 + nb * 24 + nf * 6 + kf) << 6) + lane], acc1[nf], 0, 0, 0);
        }
        // bias + GELU -> hb (wave-private rows)
        #pragma unroll
        for (int nf = 0; nf < 4; ++nf) {
            const int col = nf * 16 + ln;
            const float bias = f1b[nb * 64 + col];
            #pragma unroll
            for (int i = 0; i < 4; ++i)
                hb[m0 + ro + i][col] = f2bf(gelu_f(acc1[nf][i] + bias));
        }
        // ---- GEMM2: out += h_chunk @ f2w_chunk^T ----
        #pragma unroll
        for (int kf = 0; kf < 2; ++kf) {
            const s16x8 a = *(const s16x8*)&hb[m0 + ln][kf * 32 + ko];
            #pragma unroll
            for (int nf = 0; nf < 12; ++nf)
                acc2[nf] = __builtin_amdgcn_mfma_f32_16x16x32_bf16(
                    a, wv[((576 + nb * 24 + nf * 2 + kf) << 6) + lane], acc2[nf], 0, 0, 0);
        }
        __syncthreads();   // loose lockstep across waves for L1 weight reuse
    }

    // ---- Epilogue: + fc2 bias + residual (in-place) ----
    #pragma unroll
    for (int i = 0; i < 4; ++i) {
        const int row = m0 + ro + i;
        float* yp = y + (r0 + row) * 192;
        #pragma unroll
        for (int nf = 0; nf < 12; ++nf) {
            const int col = nf * 16 + ln;
            yp[col] = yp[col] + f2b[col] + acc2[nf][i];
        }
    }
}

extern "C" void kernel_launch(void* const* d_in, const int* in_sizes, int n_in,
                              void* d_out, int out_size, void* d_ws, size_t ws_size,
                              hipStream_t stream) {
    (void)in_sizes; (void)n_in; (void)ws_size; (void)out_size;
    const float* x    = (const float*)d_in[0];
    const float* mask = (const float*)d_in[1];
    const float* g1   = (const float*)d_in[2];
    const float* b1   = (const float*)d_in[3];
    const float* qkvw = (const float*)d_in[4];
    const float* qkvb = (const float*)d_in[5];
    const float* rpb  = (const float*)d_in[6];
    const float* pw   = (const float*)d_in[7];
    const float* pb   = (const float*)d_in[8];
    const float* g2   = (const float*)d_in[9];
    const float* b2   = (const float*)d_in[10];
    const float* f1w  = (const float*)d_in[11];
    const float* f1b  = (const float*)d_in[12];
    const float* f2w  = (const float*)d_in[13];
    const float* f2b  = (const float*)d_in[14];
    float* y = (float*)d_out;
    unsigned short* wpk = (unsigned short*)d_ws;   // 884,736 B used

    pack_w<<<dim3(216), dim3(256), 0, stream>>>(qkvw, pw, f1w, f2w, wpk);
    swin_attn<<<dim3(64 * 64), dim3(256), 0, stream>>>(
        x, mask, g1, b1, wpk, qkvb, rpb, pb, y);
    swin_mlp<<<dim3(3136), dim3(256), 0, stream>>>(
        g2, b2, wpk, f1b, f2b, y);
}

// Round 4
// 1107.907 us; speedup vs baseline: 40.9834x; 1.5402x over previous
//
#include <hip/hip_runtime.h>
#include <hip/hip_bf16.h>
#include <math.h>

typedef __attribute__((ext_vector_type(8))) short s16x8;
typedef __attribute__((ext_vector_type(4))) float f32x4;

static constexpr float cSCALE = 0.17677669529663687f; // 32^-0.5

__device__ __forceinline__ float bf2f(unsigned short u) {
    union { unsigned int i; float f; } c; c.i = ((unsigned int)u) << 16; return c.f;
}
__device__ __forceinline__ unsigned short f2bf(float f) {
    union { float f; unsigned int i; } c; c.f = f;
    unsigned int r = c.i + (0x7fffu + ((c.i >> 16) & 1u));
    return (unsigned short)(r >> 16);
}
__device__ __forceinline__ s16x8 cvt8(const float4 a, const float4 b) {
    s16x8 r;
    r[0]=(short)f2bf(a.x); r[1]=(short)f2bf(a.y); r[2]=(short)f2bf(a.z); r[3]=(short)f2bf(a.w);
    r[4]=(short)f2bf(b.x); r[5]=(short)f2bf(b.y); r[6]=(short)f2bf(b.z); r[7]=(short)f2bf(b.w);
    return r;
}
__device__ __forceinline__ float gelu_f(float t) {
    const float u = 1.5957691216057308f * t * (1.0f + 0.044715f * t * t);
    return t / (1.0f + __expf(-u));
}

#define GLDS16(gp, lp) __builtin_amdgcn_global_load_lds( \
    (const __attribute__((address_space(1))) void*)(gp), \
    (__attribute__((address_space(3))) void*)(lp), 16, 0, 0)

// ============ Prep: pack weights to bf16 MFMA-fragment layout in d_ws ============
// fid: [0,216)   qkv : fid = h*36 + nf*6 + kf
//      [216,288) proj: fid = 216 + h*12 + nf
//      [288,864) mlp : fid = 288 + c*24 + j ; j<12: fc1 chunk c (nf=j/6,kf=j%6)
//                                             j>=12: fc2 chunk c (nf=j-12)
// element: ws[fid*512 + lane*8 + j] = W[row(lane)][k0 + (lane>>4)*8 + j]
__global__ __launch_bounds__(256)
void pack_w(const float* __restrict__ qkvw, const float* __restrict__ pw,
            const float* __restrict__ f1w, const float* __restrict__ f2w,
            unsigned short* __restrict__ o)
{
    const int t = blockIdx.x * 256 + threadIdx.x; // 0..55295
    const int lane = t & 63, f = t >> 6;
    const int ln = lane & 15, ko = (lane >> 4) * 8;
    const float* src;
    if (f < 216) {
        const int h = f / 36, r = f - h * 36, nf = r / 6, kf = r - nf * 6;
        src = qkvw + (size_t)((nf >> 1) * 192 + h * 32 + (nf & 1) * 16 + ln) * 192 + kf * 32 + ko;
    } else if (f < 288) {
        const int g = f - 216, h = g / 12, nf = g - h * 12;
        src = pw + (size_t)(nf * 16 + ln) * 192 + h * 32 + ko;
    } else {
        const int g = f - 288;          // 0..575
        const int c = g / 24, r24 = g - c * 24;
        if (r24 < 12) {                 // fc1 chunk c: rows c*32..+32, k full 192
            const int nf = r24 / 6, kf = r24 - nf * 6;
            src = f1w + (size_t)(c * 32 + nf * 16 + ln) * 192 + kf * 32 + ko;
        } else {                        // fc2 chunk c: rows 0..192, k = c*32..+32
            const int nf = r24 - 12;
            src = f2w + (size_t)(nf * 16 + ln) * 768 + c * 32 + ko;
        }
    }
    *(s16x8*)(o + (size_t)t * 8) = cvt8(*(const float4*)src, *(const float4*)(src + 4));
}

// stage one 12 KB fragment sub-chunk (12 fids) into LDS, async
__device__ __forceinline__ void stage12k(const unsigned short* __restrict__ wp, int sub,
                                         unsigned short* dst, int tid) {
    const unsigned short* g = wp + (((size_t)(288 + sub * 12)) << 9) + tid * 8;
    unsigned short* l = dst + tid * 8;
    #pragma unroll
    for (int i = 0; i < 3; ++i)
        GLDS16(g + i * 2048, l + i * 2048);
}

// ============ Kernel A: LN1 + shift/window + MFMA attention + proj + residual ============
__global__ __launch_bounds__(256, 3)
void swin_attn(const float* __restrict__ x, const float* __restrict__ mask,
               const float* __restrict__ g1, const float* __restrict__ b1,
               const unsigned short* __restrict__ wp, const float* __restrict__ qkvb,
               const float* __restrict__ rpb, const float* __restrict__ pb,
               float* __restrict__ y)
{
    __shared__ __align__(16) unsigned short win_[64][200]; // 25600 B
    __shared__ __align__(16) unsigned short qo_[64][40];   // 5120 (Q then attn-out; wave-private)
    __shared__ __align__(16) unsigned short k_[64][40];    // 5120
    __shared__ __align__(16) unsigned short vt_[32][72];   // 4608 (V^T [d][token])
    __shared__ __align__(16) unsigned short p_[64][72];    // 9216 (probs; rows wave-private)
    __shared__ __align__(16) unsigned short rp_[1016];     // 2032 (rpb bf16)
    // total 51696 B -> 3 blocks/CU

    const s16x8* wv = (const s16x8*)wp;
    const int w  = blockIdx.x;
    const int bb = w >> 6, wi = w & 63;
    const int wh = wi >> 3, ww = wi & 7;
    const int tid = threadIdx.x, lane = tid & 63, wave = tid >> 6;
    const int ln = lane & 15, ko = (lane >> 4) * 8, ro = (lane >> 4) * 4;
    const int m0 = wave * 16;

    // ---- LN1 + shifted gather (rows 49-63 zeroed) ----
    for (int r = wave; r < 64; r += 4) {
        if (r < 49) {
            const int p = r / 7, q7 = r - p * 7;
            int i2 = wh * 7 + p + 3;  if (i2 >= 56) i2 -= 56;
            int j2 = ww * 7 + q7 + 3; if (j2 >= 56) j2 -= 56;
            const float* xr = x + ((size_t)(bb * 56 + i2) * 56 + j2) * 192;
            const float a0 = xr[lane], a1 = xr[lane + 64], a2 = xr[lane + 128];
            float sm = a0 + a1 + a2, sq = a0*a0 + a1*a1 + a2*a2;
            #pragma unroll
            for (int o = 32; o > 0; o >>= 1) { sm += __shfl_down(sm, o); sq += __shfl_down(sq, o); }
            sm = __shfl(sm, 0); sq = __shfl(sq, 0);
            const float mean = sm * (1.0f / 192.0f);
            const float rstd = rsqrtf(sq * (1.0f / 192.0f) - mean * mean + 1e-5f);
            win_[r][lane]       = f2bf((a0 - mean) * rstd * g1[lane]       + b1[lane]);
            win_[r][lane + 64]  = f2bf((a1 - mean) * rstd * g1[lane + 64]  + b1[lane + 64]);
            win_[r][lane + 128] = f2bf((a2 - mean) * rstd * g1[lane + 128] + b1[lane + 128]);
        } else {
            win_[r][lane] = 0; win_[r][lane + 64] = 0; win_[r][lane + 128] = 0;
        }
    }
    for (int t = tid; t < 1014; t += 256) rp_[t] = f2bf(rpb[t]);
    __syncthreads();

    // hoist A fragments (wave rows m0+ln), shared across all heads
    s16x8 xa[6];
    #pragma unroll
    for (int kf = 0; kf < 6; ++kf) xa[kf] = *(const s16x8*)&win_[m0 + ln][kf * 32 + ko];

    f32x4 accp[12];
    #pragma unroll
    for (int i = 0; i < 12; ++i) accp[i] = f32x4{0.f,0.f,0.f,0.f};

    for (int h = 0; h < 6; ++h) {
        // ---- QKV: [64x96], 2-deep B prefetch ----
        const s16x8* wq = wv + ((size_t)(h * 36) << 6);
        f32x4 acc[6];
        #pragma unroll
        for (int i = 0; i < 6; ++i) acc[i] = f32x4{0.f,0.f,0.f,0.f};
        s16x8 pA[6], pB[6];
        #pragma unroll
        for (int nf = 0; nf < 6; ++nf) pA[nf] = wq[(nf * 6 + 0) * 64 + lane];
        #pragma unroll
        for (int kf = 0; kf < 6; ++kf) {
            const s16x8* cb = (kf & 1) ? pB : pA;
            s16x8*       nb = (kf & 1) ? pA : pB;
            if (kf < 5) {
                #pragma unroll
                for (int nf = 0; nf < 6; ++nf) nb[nf] = wq[(nf * 6 + kf + 1) * 64 + lane];
            }
            #pragma unroll
            for (int nf = 0; nf < 6; ++nf)
                acc[nf] = __builtin_amdgcn_mfma_f32_16x16x32_bf16(xa[kf], cb[nf], acc[nf], 0, 0, 0);
        }
        #pragma unroll
        for (int nf = 0; nf < 6; ++nf) {
            const int col = nf * 16 + ln;
            #pragma unroll
            for (int i = 0; i < 4; ++i) {
                const int row = m0 + ro + i;
                const float v = acc[nf][i];
                if (nf < 2)      qo_[row][col]       = f2bf((v + qkvb[h*32 + col]) * cSCALE);
                else if (nf < 4) k_[row][col - 32]   = f2bf(v + qkvb[192 + h*32 + col - 32]);
                else             vt_[col - 64][row]  = f2bf(v + qkvb[384 + h*32 + col - 64]);
            }
        }
        __syncthreads();   // k_/vt_ cross-wave

        // ---- S = Q @ K^T + bias + mask, softmax -> p_ (rows wave-private) ----
        f32x4 s[4];
        {
            const s16x8 aq = *(const s16x8*)&qo_[m0 + ln][ko];
            #pragma unroll
            for (int nf = 0; nf < 4; ++nf) {
                const s16x8 bk = *(const s16x8*)&k_[nf * 16 + ln][ko];
                s[nf] = __builtin_amdgcn_mfma_f32_16x16x32_bf16(aq, bk, f32x4{0.f,0.f,0.f,0.f}, 0, 0, 0);
            }
        }
        const float* mrow = mask + (size_t)wi * 2401;
        #pragma unroll
        for (int i = 0; i < 4; ++i) {
            const int n = m0 + ro + i;
            float v[4];
            #pragma unroll
            for (int nf = 0; nf < 4; ++nf) {
                const int m = nf * 16 + ln;
                float t = s[nf][i];
                if (m >= 49) t = -1e30f;
                else if (n < 49) {
                    const int p1 = n / 7, q1 = n - p1 * 7, p2 = m / 7, q2 = m - p2 * 7;
                    const int ridx = (p1 - p2 + 6) * 13 + (q1 - q2 + 6);
                    t += bf2f(rp_[ridx * 6 + h]) + mrow[n * 49 + m];
                }
                v[nf] = t;
            }
            float mx = fmaxf(fmaxf(v[0], v[1]), fmaxf(v[2], v[3]));
            #pragma unroll
            for (int o = 1; o < 16; o <<= 1) mx = fmaxf(mx, __shfl_xor(mx, o));
            float e[4], ssum = 0.f;
            #pragma unroll
            for (int nf = 0; nf < 4; ++nf) { e[nf] = __expf(v[nf] - mx); ssum += e[nf]; }
            #pragma unroll
            for (int o = 1; o < 16; o <<= 1) ssum += __shfl_xor(ssum, o);
            const float inv = 1.0f / ssum;
            #pragma unroll
            for (int nf = 0; nf < 4; ++nf) p_[n][nf * 16 + ln] = f2bf(e[nf] * inv);
        }

        // ---- O = P @ V [64x32] -> qo_ (wave-private) ----
        f32x4 o[2];
        #pragma unroll
        for (int i = 0; i < 2; ++i) o[i] = f32x4{0.f,0.f,0.f,0.f};
        #pragma unroll
        for (int kf = 0; kf < 2; ++kf) {
            const s16x8 ap = *(const s16x8*)&p_[m0 + ln][kf * 32 + ko];
            #pragma unroll
            for (int nf = 0; nf < 2; ++nf) {
                const s16x8 bv = *(const s16x8*)&vt_[nf * 16 + ln][kf * 32 + ko];
                o[nf] = __builtin_amdgcn_mfma_f32_16x16x32_bf16(ap, bv, o[nf], 0, 0, 0);
            }
        }
        #pragma unroll
        for (int nf = 0; nf < 2; ++nf)
            #pragma unroll
            for (int i = 0; i < 4; ++i)
                qo_[m0 + ro + i][nf * 16 + ln] = f2bf(o[nf][i]);

        // ---- proj partial, 2-batch prefetch (A wave-private) ----
        {
            const s16x8* wpj = wv + ((size_t)(216 + h * 12) << 6);
            #pragma unroll
            for (int nf = 0; nf < 6; ++nf) pA[nf] = wpj[nf * 64 + lane];
            const s16x8 ao = *(const s16x8*)&qo_[m0 + ln][ko];
            #pragma unroll
            for (int nf = 0; nf < 6; ++nf) pB[nf] = wpj[(6 + nf) * 64 + lane];
            #pragma unroll
            for (int nf = 0; nf < 6; ++nf)
                accp[nf] = __builtin_amdgcn_mfma_f32_16x16x32_bf16(ao, pA[nf], accp[nf], 0, 0, 0);
            #pragma unroll
            for (int nf = 0; nf < 6; ++nf)
                accp[6 + nf] = __builtin_amdgcn_mfma_f32_16x16x32_bf16(ao, pB[nf], accp[6 + nf], 0, 0, 0);
        }
        __syncthreads();   // protect k_/vt_/p_ before next head overwrites
    }

    // ---- Epilogue: + proj bias + residual, scatter to shifted coords ----
    #pragma unroll
    for (int i = 0; i < 4; ++i) {
        const int n = m0 + ro + i;
        if (n < 49) {
            const int p = n / 7, q7 = n - p * 7;
            int i2 = wh * 7 + p + 3;  if (i2 >= 56) i2 -= 56;
            int j2 = ww * 7 + q7 + 3; if (j2 >= 56) j2 -= 56;
            const size_t base = ((size_t)(bb * 56 + i2) * 56 + j2) * 192;
            #pragma unroll
            for (int nf = 0; nf < 12; ++nf) {
                const int col = nf * 16 + ln;
                y[base + col] = x[base + col] + pb[col] + accp[nf][i];
            }
        }
    }
}

// ============ Kernel B: LN2 + fc1 + GELU + fc2 + residual (async-staged weights) ============
__global__ __launch_bounds__(256)
void swin_mlp(const float* __restrict__ g2, const float* __restrict__ b2,
              const unsigned short* __restrict__ wp,
              const float* __restrict__ f1b, const float* __restrict__ f2b,
              float* __restrict__ y)
{
    __shared__ __align__(16) unsigned short xnf[6][64][32]; // 24576 B (LN'd rows, frag-chunked)
    __shared__ __align__(16) unsigned short hb[64][40];     // 5120 B (rows wave-private)
    __shared__ __align__(16) unsigned short wst0[6144];     // 12288 B (fc1 chunk frags)
    __shared__ __align__(16) unsigned short wst1[6144];     // 12288 B (fc2 chunk frags)
    // total 54272 B -> 3 blocks/CU

    const int tid = threadIdx.x, lane = tid & 63, wave = tid >> 6;
    const int ln = lane & 15, ko = (lane >> 4) * 8, ro = (lane >> 4) * 4;
    const int m0 = wave * 16;
    const size_t r0 = (size_t)blockIdx.x * 64;

    // ---- LN2 -> xnf (bf16) ----
    for (int r = wave; r < 64; r += 4) {
        const float* yr = y + (r0 + r) * 192;
        const float a0 = yr[lane], a1 = yr[lane + 64], a2 = yr[lane + 128];
        float sm = a0 + a1 + a2, sq = a0*a0 + a1*a1 + a2*a2;
        #pragma unroll
        for (int o = 32; o > 0; o >>= 1) { sm += __shfl_down(sm, o); sq += __shfl_down(sq, o); }
        sm = __shfl(sm, 0); sq = __shfl(sq, 0);
        const float mean = sm * (1.0f / 192.0f);
        const float rstd = rsqrtf(sq * (1.0f / 192.0f) - mean * mean + 1e-5f);
        const int c0 = lane, c1 = lane + 64, c2 = lane + 128;
        xnf[c0 >> 5][r][c0 & 31] = f2bf((a0 - mean) * rstd * g2[c0] + b2[c0]);
        xnf[c1 >> 5][r][c1 & 31] = f2bf((a1 - mean) * rstd * g2[c1] + b2[c1]);
        xnf[c2 >> 5][r][c2 & 31] = f2bf((a2 - mean) * rstd * g2[c2] + b2[c2]);
    }
    stage12k(wp, 0, wst0, tid);      // fc1 chunk 0
    __syncthreads();                 // LN visible + stage 0 complete

    // hoist A fragments (wave rows m0+ln) for all 24 fc1 chunks
    s16x8 xa[6];
    #pragma unroll
    for (int kf = 0; kf < 6; ++kf) xa[kf] = *(const s16x8*)&xnf[kf][m0 + ln][ko];

    f32x4 acc2[12];
    #pragma unroll
    for (int i = 0; i < 12; ++i) acc2[i] = f32x4{0.f,0.f,0.f,0.f};

    for (int c = 0; c < 24; ++c) {
        stage12k(wp, 2 * c + 1, wst1, tid);   // fc2 chunk c, overlaps G1
        // ---- G1: h_chunk[64x32] = xn @ fc1_c^T ----
        const s16x8* wb1 = (const s16x8*)wst0;
        f32x4 acc1[2];
        acc1[0] = f32x4{0.f,0.f,0.f,0.f}; acc1[1] = f32x4{0.f,0.f,0.f,0.f};
        #pragma unroll
        for (int kf = 0; kf < 6; ++kf) {
            #pragma unroll
            for (int nf = 0; nf < 2; ++nf)
                acc1[nf] = __builtin_amdgcn_mfma_f32_16x16x32_bf16(
                    xa[kf], wb1[(nf * 6 + kf) * 64 + lane], acc1[nf], 0, 0, 0);
        }
        __syncthreads();   // wst1 staged; all waves done reading wst0
        if (c < 23) stage12k(wp, 2 * c + 2, wst0, tid);  // fc1 chunk c+1, overlaps G2
        // ---- bias + GELU -> hb (wave-private rows) ----
        #pragma unroll
        for (int nf = 0; nf < 2; ++nf) {
            const int col = nf * 16 + ln;
            const float bias = f1b[c * 32 + col];
            #pragma unroll
            for (int i = 0; i < 4; ++i)
                hb[m0 + ro + i][col] = f2bf(gelu_f(acc1[nf][i] + bias));
        }
        // ---- G2: out += h_chunk @ fc2_c^T ----
        const s16x8 ah = *(const s16x8*)&hb[m0 + ln][ko];
        const s16x8* wb2 = (const s16x8*)wst1;
        #pragma unroll
        for (int nf = 0; nf < 12; ++nf)
            acc2[nf] = __builtin_amdgcn_mfma_f32_16x16x32_bf16(
                ah, wb2[nf * 64 + lane], acc2[nf], 0, 0, 0);
        __syncthreads();   // wst0 staged for next c; all waves done reading wst1
    }

    // ---- Epilogue: + fc2 bias + residual (in-place) ----
    #pragma unroll
    for (int i = 0; i < 4; ++i) {
        const int row = m0 + ro + i;
        float* yp = y + (r0 + row) * 192;
        #pragma unroll
        for (int nf = 0; nf < 12; ++nf) {
            const int col = nf * 16 + ln;
            yp[col] = yp[col] + f2b[col] + acc2[nf][i];
        }
    }
}

extern "C" void kernel_launch(void* const* d_in, const int* in_sizes, int n_in,
                              void* d_out, int out_size, void* d_ws, size_t ws_size,
                              hipStream_t stream) {
    (void)in_sizes; (void)n_in; (void)ws_size; (void)out_size;
    const float* x    = (const float*)d_in[0];
    const float* mask = (const float*)d_in[1];
    const float* g1   = (const float*)d_in[2];
    const float* b1   = (const float*)d_in[3];
    const float* qkvw = (const float*)d_in[4];
    const float* qkvb = (const float*)d_in[5];
    const float* rpb  = (const float*)d_in[6];
    const float* pw   = (const float*)d_in[7];
    const float* pb   = (const float*)d_in[8];
    const float* g2   = (const float*)d_in[9];
    const float* b2   = (const float*)d_in[10];
    const float* f1w  = (const float*)d_in[11];
    const float* f1b  = (const float*)d_in[12];
    const float* f2w  = (const float*)d_in[13];
    const float* f2b  = (const float*)d_in[14];
    float* y = (float*)d_out;
    unsigned short* wpk = (unsigned short*)d_ws;   // 884,736 B used

    pack_w<<<dim3(216), dim3(256), 0, stream>>>(qkvw, pw, f1w, f2w, wpk);
    swin_attn<<<dim3(64 * 64), dim3(256), 0, stream>>>(
        x, mask, g1, b1, wpk, qkvb, rpb, pb, y);
    swin_mlp<<<dim3(3136), dim3(256), 0, stream>>>(
        g2, b2, wpk, f1b, f2b, y);
}

// Round 5
// 705.559 us; speedup vs baseline: 64.3543x; 1.5703x over previous
//
#include <hip/hip_runtime.h>
#include <hip/hip_bf16.h>
#include <math.h>

typedef __attribute__((ext_vector_type(8))) short s16x8;
typedef __attribute__((ext_vector_type(4))) float f32x4;

static constexpr float cSCALE = 0.17677669529663687f; // 32^-0.5

__device__ __forceinline__ float bf2f(unsigned short u) {
    union { unsigned int i; float f; } c; c.i = ((unsigned int)u) << 16; return c.f;
}
__device__ __forceinline__ unsigned short f2bf(float f) {
    union { float f; unsigned int i; } c; c.f = f;
    unsigned int r = c.i + (0x7fffu + ((c.i >> 16) & 1u));
    return (unsigned short)(r >> 16);
}
__device__ __forceinline__ s16x8 cvt8(const float4 a, const float4 b) {
    s16x8 r;
    r[0]=(short)f2bf(a.x); r[1]=(short)f2bf(a.y); r[2]=(short)f2bf(a.z); r[3]=(short)f2bf(a.w);
    r[4]=(short)f2bf(b.x); r[5]=(short)f2bf(b.y); r[6]=(short)f2bf(b.z); r[7]=(short)f2bf(b.w);
    return r;
}
__device__ __forceinline__ float gelu_f(float t) {
    const float u = 1.5957691216057308f * t * (1.0f + 0.044715f * t * t);
    return t / (1.0f + __expf(-u));
}

#define GLDS16(gp, lp) __builtin_amdgcn_global_load_lds( \
    (const __attribute__((address_space(1))) void*)(gp), \
    (__attribute__((address_space(3))) void*)(lp), 16, 0, 0)

// In-register LayerNorm of one 192-col row, produces 6 MFMA A-fragments.
// Thread (ln,hi) owns cols {hi*8..hi*8+7} + 32k; stats reduced across hi via shfl_xor.
__device__ __forceinline__ void ln_frag(const float* __restrict__ rowp,
                                        const float* __restrict__ g,
                                        const float* __restrict__ b,
                                        int hi, s16x8* xa)
{
    float4 v[12];
    #pragma unroll
    for (int k = 0; k < 6; ++k) {
        v[2*k]   = *(const float4*)(rowp + k*32 + hi*8);
        v[2*k+1] = *(const float4*)(rowp + k*32 + hi*8 + 4);
    }
    float sm = 0.f, sq = 0.f;
    #pragma unroll
    for (int i = 0; i < 12; ++i) {
        sm += (v[i].x + v[i].y) + (v[i].z + v[i].w);
        sq += (v[i].x*v[i].x + v[i].y*v[i].y) + (v[i].z*v[i].z + v[i].w*v[i].w);
    }
    sm += __shfl_xor(sm, 16); sq += __shfl_xor(sq, 16);
    sm += __shfl_xor(sm, 32); sq += __shfl_xor(sq, 32);
    const float mean = sm * (1.0f/192.0f);
    const float rstd = rsqrtf(sq * (1.0f/192.0f) - mean*mean + 1e-5f);
    #pragma unroll
    for (int k = 0; k < 6; ++k) {
        const float4 ga = *(const float4*)(g + k*32 + hi*8);
        const float4 gb = *(const float4*)(g + k*32 + hi*8 + 4);
        const float4 ba = *(const float4*)(b + k*32 + hi*8);
        const float4 bb = *(const float4*)(b + k*32 + hi*8 + 4);
        s16x8 r;
        r[0] = (short)f2bf((v[2*k].x  -mean)*rstd*ga.x + ba.x);
        r[1] = (short)f2bf((v[2*k].y  -mean)*rstd*ga.y + ba.y);
        r[2] = (short)f2bf((v[2*k].z  -mean)*rstd*ga.z + ba.z);
        r[3] = (short)f2bf((v[2*k].w  -mean)*rstd*ga.w + ba.w);
        r[4] = (short)f2bf((v[2*k+1].x-mean)*rstd*gb.x + bb.x);
        r[5] = (short)f2bf((v[2*k+1].y-mean)*rstd*gb.y + bb.y);
        r[6] = (short)f2bf((v[2*k+1].z-mean)*rstd*gb.z + bb.z);
        r[7] = (short)f2bf((v[2*k+1].w-mean)*rstd*gb.w + bb.w);
        xa[k] = r;
    }
}

// ============ Prep 1: pack weights to bf16 MFMA-fragment layout in d_ws ============
// fid: [0,216)   qkv : fid = h*36 + nf*6 + kf
//      [216,288) proj: fid = 216 + h*12 + nf
//      [288,864) mlp : fid = 288 + c*24 + j ; j<12: fc1 chunk c ; j>=12: fc2 chunk c
__global__ __launch_bounds__(256)
void pack_w(const float* __restrict__ qkvw, const float* __restrict__ pw,
            const float* __restrict__ f1w, const float* __restrict__ f2w,
            unsigned short* __restrict__ o)
{
    const int t = blockIdx.x * 256 + threadIdx.x; // 0..55295
    const int lane = t & 63, f = t >> 6;
    const int ln = lane & 15, ko = (lane >> 4) * 8;
    const float* src;
    if (f < 216) {
        const int h = f / 36, r = f - h * 36, nf = r / 6, kf = r - nf * 6;
        src = qkvw + (size_t)((nf >> 1) * 192 + h * 32 + (nf & 1) * 16 + ln) * 192 + kf * 32 + ko;
    } else if (f < 288) {
        const int g = f - 216, h = g / 12, nf = g - h * 12;
        src = pw + (size_t)(nf * 16 + ln) * 192 + h * 32 + ko;
    } else {
        const int g = f - 288;
        const int c = g / 24, r24 = g - c * 24;
        if (r24 < 12) {
            const int nf = r24 / 6, kf = r24 - nf * 6;
            src = f1w + (size_t)(c * 32 + nf * 16 + ln) * 192 + kf * 32 + ko;
        } else {
            const int nf = r24 - 12;
            src = f2w + (size_t)(nf * 16 + ln) * 768 + c * 32 + ko;
        }
    }
    *(s16x8*)(o + (size_t)t * 8) = cvt8(*(const float4*)src, *(const float4*)(src + 4));
}

// ============ Prep 2: fold rpb + shift-mask into per-(window,head) bias [49][64] bf16 ============
__global__ __launch_bounds__(256)
void pack_bias(const float* __restrict__ mask, const float* __restrict__ rpb,
               unsigned short* __restrict__ o)
{
    const int wi = blockIdx.x / 6, h = blockIdx.x - wi * 6;
    for (int t = threadIdx.x; t < 49 * 64; t += 256) {
        const int n = t >> 6, m = t & 63;
        float v = 0.f;
        if (m < 49) {
            const int p1 = n / 7, q1 = n - p1 * 7, p2 = m / 7, q2 = m - p2 * 7;
            const int ridx = (p1 - p2 + 6) * 13 + (q1 - q2 + 6);
            v = rpb[ridx * 6 + h] + mask[(size_t)wi * 2401 + n * 49 + m];
        }
        o[((size_t)(wi * 6 + h) * 49 + n) * 64 + m] = f2bf(v);
    }
}

// stage one 12 KB fragment sub-chunk (12 fids) into LDS, async
__device__ __forceinline__ void stage12k(const unsigned short* __restrict__ wp, int sub,
                                         unsigned short* dst, int tid) {
    const unsigned short* g = wp + (((size_t)(288 + sub * 12)) << 9) + tid * 8;
    unsigned short* l = dst + tid * 8;
    #pragma unroll
    for (int i = 0; i < 3; ++i)
        GLDS16(g + i * 2048, l + i * 2048);
}

// ============ Kernel A: LN1 + shift/window + MFMA attention + proj + residual ============
__global__ __launch_bounds__(256)
void swin_attn(const float* __restrict__ x, const float* __restrict__ g1,
               const float* __restrict__ b1, const unsigned short* __restrict__ wp,
               const unsigned short* __restrict__ bias_g,
               const float* __restrict__ qkvb, const float* __restrict__ pb,
               float* __restrict__ y)
{
    __shared__ __align__(16) unsigned short qo_[64][40];   // 5120 (Q then attn-out; wave-private rows)
    __shared__ __align__(16) unsigned short k_[64][40];    // 5120
    __shared__ __align__(16) unsigned short vt_[32][72];   // 4608 (V^T [d][token])
    __shared__ __align__(16) unsigned short p_[64][72];    // 9216 (probs; rows wave-private)
    // total 24064 B

    const s16x8* wv = (const s16x8*)wp;
    const int w  = blockIdx.x;
    const int bb = w >> 6, wi = w & 63;
    const int wh = wi >> 3, ww = wi & 7;
    const int tid = threadIdx.x, lane = tid & 63, wave = tid >> 6;
    const int ln = lane & 15, hi = lane >> 4, ko = hi * 8, ro = hi * 4;
    const int m0 = wave * 16;

    // ---- LN1 fully in registers: thread (ln,hi) owns token m0+ln ----
    s16x8 xa[6];
    {
        const int t = m0 + ln;
        const int p = t / 7, q7 = t - p * 7;
        int i2 = wh * 7 + p + 3;  if (i2 >= 56) i2 -= 56;
        int j2 = ww * 7 + q7 + 3; if (j2 >= 56) j2 -= 56;
        const float* xr = x + ((size_t)(bb * 56 + i2) * 56 + j2) * 192;
        ln_frag(xr, g1, b1, hi, xa);
        if (t >= 49) {
            #pragma unroll
            for (int k = 0; k < 6; ++k) xa[k] = s16x8{0,0,0,0,0,0,0,0};
        }
    }

    f32x4 accp[12];
    #pragma unroll
    for (int i = 0; i < 12; ++i) accp[i] = f32x4{0.f,0.f,0.f,0.f};

    for (int h = 0; h < 6; ++h) {
        // ---- QKV: [64x96], nf-outer (low register footprint, static arrays only) ----
        const s16x8* wq = wv + ((size_t)(h * 36) << 6);
        #pragma unroll
        for (int nf = 0; nf < 6; ++nf) {
            s16x8 bf6[6];
            #pragma unroll
            for (int kf = 0; kf < 6; ++kf) bf6[kf] = wq[(nf * 6 + kf) * 64 + lane];
            f32x4 a = f32x4{0.f,0.f,0.f,0.f};
            #pragma unroll
            for (int kf = 0; kf < 6; ++kf)
                a = __builtin_amdgcn_mfma_f32_16x16x32_bf16(xa[kf], bf6[kf], a, 0, 0, 0);
            const int col = nf * 16 + ln;
            #pragma unroll
            for (int i = 0; i < 4; ++i) {
                const int row = m0 + ro + i;
                const float v = a[i];
                if (nf < 2)      qo_[row][col]       = f2bf((v + qkvb[h*32 + col]) * cSCALE);
                else if (nf < 4) k_[row][col - 32]   = f2bf(v + qkvb[192 + h*32 + col - 32]);
                else             vt_[col - 64][row]  = f2bf(v + qkvb[384 + h*32 + col - 64]);
            }
        }
        __syncthreads();   // k_/vt_ cross-wave

        // ---- S = Q @ K^T (wave rows only) + fused bias, softmax -> p_ ----
        f32x4 s4[4];
        {
            const s16x8 aq = *(const s16x8*)&qo_[m0 + ln][ko];
            #pragma unroll
            for (int nf = 0; nf < 4; ++nf) {
                const s16x8 bk = *(const s16x8*)&k_[nf * 16 + ln][ko];
                s4[nf] = __builtin_amdgcn_mfma_f32_16x16x32_bf16(aq, bk, f32x4{0.f,0.f,0.f,0.f}, 0, 0, 0);
            }
        }
        const unsigned short* bg = bias_g + (size_t)(wi * 6 + h) * 49 * 64;
        #pragma unroll
        for (int i = 0; i < 4; ++i) {
            const int n = m0 + ro + i;
            float vv[4];
            #pragma unroll
            for (int nf = 0; nf < 4; ++nf) {
                const int m = nf * 16 + ln;
                float tv = s4[nf][i];
                if (m >= 49) tv = -1e30f;
                else if (n < 49) tv += bf2f(bg[n * 64 + m]);
                vv[nf] = tv;
            }
            float mx = fmaxf(fmaxf(vv[0], vv[1]), fmaxf(vv[2], vv[3]));
            #pragma unroll
            for (int o = 1; o < 16; o <<= 1) mx = fmaxf(mx, __shfl_xor(mx, o));
            const float e0 = __expf(vv[0]-mx), e1 = __expf(vv[1]-mx);
            const float e2 = __expf(vv[2]-mx), e3 = __expf(vv[3]-mx);
            float ssum = (e0 + e1) + (e2 + e3);
            #pragma unroll
            for (int o = 1; o < 16; o <<= 1) ssum += __shfl_xor(ssum, o);
            const float inv = 1.0f / ssum;
            p_[n][     ln] = f2bf(e0 * inv);
            p_[n][16 + ln] = f2bf(e1 * inv);
            p_[n][32 + ln] = f2bf(e2 * inv);
            p_[n][48 + ln] = f2bf(e3 * inv);
        }

        // ---- O = P @ V (wave rows) -> qo_ ----
        f32x4 o2[2];
        o2[0] = f32x4{0.f,0.f,0.f,0.f}; o2[1] = f32x4{0.f,0.f,0.f,0.f};
        #pragma unroll
        for (int kf = 0; kf < 2; ++kf) {
            const s16x8 ap = *(const s16x8*)&p_[m0 + ln][kf * 32 + ko];
            #pragma unroll
            for (int nf = 0; nf < 2; ++nf) {
                const s16x8 bv = *(const s16x8*)&vt_[nf * 16 + ln][kf * 32 + ko];
                o2[nf] = __builtin_amdgcn_mfma_f32_16x16x32_bf16(ap, bv, o2[nf], 0, 0, 0);
            }
        }
        #pragma unroll
        for (int nf = 0; nf < 2; ++nf)
            #pragma unroll
            for (int i = 0; i < 4; ++i)
                qo_[m0 + ro + i][nf * 16 + ln] = f2bf(o2[nf][i]);

        // ---- proj partial: two static half-batches of 6 ----
        {
            const s16x8 ao = *(const s16x8*)&qo_[m0 + ln][ko];
            const s16x8* wpj = wv + ((size_t)(216 + h * 12) << 6);
            #pragma unroll
            for (int half = 0; half < 2; ++half) {
                s16x8 bf6[6];
                #pragma unroll
                for (int nf = 0; nf < 6; ++nf) bf6[nf] = wpj[(half * 6 + nf) * 64 + lane];
                #pragma unroll
                for (int nf = 0; nf < 6; ++nf)
                    accp[half * 6 + nf] = __builtin_amdgcn_mfma_f32_16x16x32_bf16(
                        ao, bf6[nf], accp[half * 6 + nf], 0, 0, 0);
            }
        }
        __syncthreads();   // protect k_/vt_/p_ before next head overwrites
    }

    // ---- Epilogue: + proj bias + residual, scatter to shifted coords ----
    #pragma unroll
    for (int i = 0; i < 4; ++i) {
        const int n = m0 + ro + i;
        if (n < 49) {
            const int p = n / 7, q7 = n - p * 7;
            int i2 = wh * 7 + p + 3;  if (i2 >= 56) i2 -= 56;
            int j2 = ww * 7 + q7 + 3; if (j2 >= 56) j2 -= 56;
            const size_t base = ((size_t)(bb * 56 + i2) * 56 + j2) * 192;
            #pragma unroll
            for (int nf = 0; nf < 12; ++nf) {
                const int col = nf * 16 + ln;
                y[base + col] = x[base + col] + pb[col] + accp[nf][i];
            }
        }
    }
}

// ============ Kernel B: LN2 + fc1 + GELU + fc2 + residual (async-staged weights) ============
__global__ __launch_bounds__(256)
void swin_mlp(const float* __restrict__ g2, const float* __restrict__ b2,
              const unsigned short* __restrict__ wp,
              const float* __restrict__ f1b, const float* __restrict__ f2b,
              float* __restrict__ y)
{
    __shared__ __align__(16) unsigned short hb[64][40];     // 5120 B (rows wave-private)
    __shared__ __align__(16) unsigned short wst0[6144];     // 12288 B (fc1 chunk frags)
    __shared__ __align__(16) unsigned short wst1[6144];     // 12288 B (fc2 chunk frags)
    // total 29696 B

    const int tid = threadIdx.x, lane = tid & 63, wave = tid >> 6;
    const int ln = lane & 15, hi = lane >> 4, ko = hi * 8, ro = hi * 4;
    const int m0 = wave * 16;
    const size_t r0 = (size_t)blockIdx.x * 64;

    stage12k(wp, 0, wst0, tid);      // fc1 chunk 0 DMA overlaps the LN

    // ---- LN2 fully in registers: thread (ln,hi) owns row m0+ln ----
    s16x8 xa[6];
    ln_frag(y + (r0 + m0 + ln) * 192, g2, b2, hi, xa);
    __syncthreads();                 // stage 0 complete (vmcnt drained at barrier)

    f32x4 acc2[12];
    #pragma unroll
    for (int i = 0; i < 12; ++i) acc2[i] = f32x4{0.f,0.f,0.f,0.f};

    for (int c = 0; c < 24; ++c) {
        stage12k(wp, 2 * c + 1, wst1, tid);   // fc2 chunk c, overlaps G1
        // ---- G1: h_chunk[64x32] = xn @ fc1_c^T ----
        const s16x8* wb1 = (const s16x8*)wst0;
        f32x4 acc1[2];
        acc1[0] = f32x4{0.f,0.f,0.f,0.f}; acc1[1] = f32x4{0.f,0.f,0.f,0.f};
        #pragma unroll
        for (int kf = 0; kf < 6; ++kf) {
            #pragma unroll
            for (int nf = 0; nf < 2; ++nf)
                acc1[nf] = __builtin_amdgcn_mfma_f32_16x16x32_bf16(
                    xa[kf], wb1[(nf * 6 + kf) * 64 + lane], acc1[nf], 0, 0, 0);
        }
        __syncthreads();   // wst1 staged; all waves done reading wst0
        if (c < 23) stage12k(wp, 2 * c + 2, wst0, tid);  // fc1 chunk c+1, overlaps G2
        // ---- bias + GELU -> hb (wave-private rows) ----
        #pragma unroll
        for (int nf = 0; nf < 2; ++nf) {
            const int col = nf * 16 + ln;
            const float bias = f1b[c * 32 + col];
            #pragma unroll
            for (int i = 0; i < 4; ++i)
                hb[m0 + ro + i][col] = f2bf(gelu_f(acc1[nf][i] + bias));
        }
        // ---- G2: out += h_chunk @ fc2_c^T ----
        const s16x8 ah = *(const s16x8*)&hb[m0 + ln][ko];
        const s16x8* wb2 = (const s16x8*)wst1;
        #pragma unroll
        for (int nf = 0; nf < 12; ++nf)
            acc2[nf] = __builtin_amdgcn_mfma_f32_16x16x32_bf16(
                ah, wb2[nf * 64 + lane], acc2[nf], 0, 0, 0);
        __syncthreads();   // wst0 staged for next c; all waves done reading wst1
    }

    // ---- Epilogue: + fc2 bias + residual (in-place) ----
    #pragma unroll
    for (int i = 0; i < 4; ++i) {
        const int row = m0 + ro + i;
        float* yp = y + (r0 + row) * 192;
        #pragma unroll
        for (int nf = 0; nf < 12; ++nf) {
            const int col = nf * 16 + ln;
            yp[col] = yp[col] + f2b[col] + acc2[nf][i];
        }
    }
}

extern "C" void kernel_launch(void* const* d_in, const int* in_sizes, int n_in,
                              void* d_out, int out_size, void* d_ws, size_t ws_size,
                              hipStream_t stream) {
    (void)in_sizes; (void)n_in; (void)ws_size; (void)out_size;
    const float* x    = (const float*)d_in[0];
    const float* mask = (const float*)d_in[1];
    const float* g1   = (const float*)d_in[2];
    const float* b1   = (const float*)d_in[3];
    const float* qkvw = (const float*)d_in[4];
    const float* qkvb = (const float*)d_in[5];
    const float* rpb  = (const float*)d_in[6];
    const float* pw   = (const float*)d_in[7];
    const float* pb   = (const float*)d_in[8];
    const float* g2   = (const float*)d_in[9];
    const float* b2   = (const float*)d_in[10];
    const float* f1w  = (const float*)d_in[11];
    const float* f1b  = (const float*)d_in[12];
    const float* f2w  = (const float*)d_in[13];
    const float* f2b  = (const float*)d_in[14];
    float* y = (float*)d_out;
    unsigned short* wpk  = (unsigned short*)d_ws;          // 884,736 B
    unsigned short* bias = wpk + 442368;                   // 2,408,448 B -> total ~3.3 MB

    pack_w<<<dim3(216), dim3(256), 0, stream>>>(qkvw, pw, f1w, f2w, wpk);
    pack_bias<<<dim3(384), dim3(256), 0, stream>>>(mask, rpb, bias);
    swin_attn<<<dim3(64 * 64), dim3(256), 0, stream>>>(
        x, g1, b1, wpk, bias, qkvb, pb, y);
    swin_mlp<<<dim3(3136), dim3(256), 0, stream>>>(
        g2, b2, wpk, f1b, f2b, y);
}

// Round 6
// 536.768 us; speedup vs baseline: 84.5911x; 1.3145x over previous
//
#include <hip/hip_runtime.h>
#include <hip/hip_bf16.h>
#include <math.h>

typedef __attribute__((ext_vector_type(8))) short s16x8;
typedef __attribute__((ext_vector_type(4))) float f32x4;

static constexpr float cSCALE = 0.17677669529663687f; // 32^-0.5

__device__ __forceinline__ float bf2f(unsigned short u) {
    union { unsigned int i; float f; } c; c.i = ((unsigned int)u) << 16; return c.f;
}
__device__ __forceinline__ unsigned short f2bf(float f) {
    union { float f; unsigned int i; } c; c.f = f;
    unsigned int r = c.i + (0x7fffu + ((c.i >> 16) & 1u));
    return (unsigned short)(r >> 16);
}
__device__ __forceinline__ s16x8 cvt8(const float4 a, const float4 b) {
    s16x8 r;
    r[0]=(short)f2bf(a.x); r[1]=(short)f2bf(a.y); r[2]=(short)f2bf(a.z); r[3]=(short)f2bf(a.w);
    r[4]=(short)f2bf(b.x); r[5]=(short)f2bf(b.y); r[6]=(short)f2bf(b.z); r[7]=(short)f2bf(b.w);
    return r;
}
__device__ __forceinline__ float gelu_f(float t) {
    const float u = 1.5957691216057308f * t * (1.0f + 0.044715f * t * t);
    return t / (1.0f + __expf(-u));
}

#define GLDS16(gp, lp) __builtin_amdgcn_global_load_lds( \
    (const __attribute__((address_space(1))) void*)(gp), \
    (__attribute__((address_space(3))) void*)(lp), 16, 0, 0)

// In-register LayerNorm of one 192-col row -> 6 MFMA A-fragments.
__device__ __forceinline__ void ln_frag(const float* __restrict__ rowp,
                                        const float* __restrict__ g,
                                        const float* __restrict__ b,
                                        int hi, s16x8* xa)
{
    float4 v[12];
    #pragma unroll
    for (int k = 0; k < 6; ++k) {
        v[2*k]   = *(const float4*)(rowp + k*32 + hi*8);
        v[2*k+1] = *(const float4*)(rowp + k*32 + hi*8 + 4);
    }
    float sm = 0.f, sq = 0.f;
    #pragma unroll
    for (int i = 0; i < 12; ++i) {
        sm += (v[i].x + v[i].y) + (v[i].z + v[i].w);
        sq += (v[i].x*v[i].x + v[i].y*v[i].y) + (v[i].z*v[i].z + v[i].w*v[i].w);
    }
    sm += __shfl_xor(sm, 16); sq += __shfl_xor(sq, 16);
    sm += __shfl_xor(sm, 32); sq += __shfl_xor(sq, 32);
    const float mean = sm * (1.0f/192.0f);
    const float rstd = rsqrtf(sq * (1.0f/192.0f) - mean*mean + 1e-5f);
    #pragma unroll
    for (int k = 0; k < 6; ++k) {
        const float4 ga = *(const float4*)(g + k*32 + hi*8);
        const float4 gb = *(const float4*)(g + k*32 + hi*8 + 4);
        const float4 ba = *(const float4*)(b + k*32 + hi*8);
        const float4 bb = *(const float4*)(b + k*32 + hi*8 + 4);
        s16x8 r;
        r[0] = (short)f2bf((v[2*k].x  -mean)*rstd*ga.x + ba.x);
        r[1] = (short)f2bf((v[2*k].y  -mean)*rstd*ga.y + ba.y);
        r[2] = (short)f2bf((v[2*k].z  -mean)*rstd*ga.z + ba.z);
        r[3] = (short)f2bf((v[2*k].w  -mean)*rstd*ga.w + ba.w);
        r[4] = (short)f2bf((v[2*k+1].x-mean)*rstd*gb.x + bb.x);
        r[5] = (short)f2bf((v[2*k+1].y-mean)*rstd*gb.y + bb.y);
        r[6] = (short)f2bf((v[2*k+1].z-mean)*rstd*gb.z + bb.z);
        r[7] = (short)f2bf((v[2*k+1].w-mean)*rstd*gb.w + bb.w);
        xa[k] = r;
    }
}

// ============ Prep 1: pack weights to bf16 MFMA-fragment layout in d_ws ============
// fid: [0,216)   qkv : fid = h*36 + nf*6 + kf
//      [216,288) proj: fid = 216 + h*12 + nf
//      [288,864) mlp : fid = 288 + c*24 + j ; j<12: fc1 chunk c ; j>=12: fc2 chunk c
__global__ __launch_bounds__(256)
void pack_w(const float* __restrict__ qkvw, const float* __restrict__ pw,
            const float* __restrict__ f1w, const float* __restrict__ f2w,
            unsigned short* __restrict__ o)
{
    const int t = blockIdx.x * 256 + threadIdx.x; // 0..55295
    const int lane = t & 63, f = t >> 6;
    const int ln = lane & 15, ko = (lane >> 4) * 8;
    const float* src;
    if (f < 216) {
        const int h = f / 36, r = f - h * 36, nf = r / 6, kf = r - nf * 6;
        src = qkvw + (size_t)((nf >> 1) * 192 + h * 32 + (nf & 1) * 16 + ln) * 192 + kf * 32 + ko;
    } else if (f < 288) {
        const int g = f - 216, h = g / 12, nf = g - h * 12;
        src = pw + (size_t)(nf * 16 + ln) * 192 + h * 32 + ko;
    } else {
        const int g = f - 288;
        const int c = g / 24, r24 = g - c * 24;
        if (r24 < 12) {
            const int nf = r24 / 6, kf = r24 - nf * 6;
            src = f1w + (size_t)(c * 32 + nf * 16 + ln) * 192 + kf * 32 + ko;
        } else {
            const int nf = r24 - 12;
            src = f2w + (size_t)(nf * 16 + ln) * 768 + c * 32 + ko;
        }
    }
    *(s16x8*)(o + (size_t)t * 8) = cvt8(*(const float4*)src, *(const float4*)(src + 4));
}

// ============ Prep 2: rpb + shift-mask folded, thread-contiguous layout ============
// o[((wi*6+h)*49 + n)*64 + ln*4 + nf] = bias(n, m=nf*16+ln)
__global__ __launch_bounds__(256)
void pack_bias(const float* __restrict__ mask, const float* __restrict__ rpb,
               unsigned short* __restrict__ o)
{
    const int wi = blockIdx.x / 6, h = blockIdx.x - wi * 6;
    for (int t = threadIdx.x; t < 49 * 64; t += 256) {
        const int n = t >> 6, mm = t & 63;
        const int ln = mm >> 2, nf = mm & 3;
        const int m = nf * 16 + ln;
        float v = 0.f;
        if (m < 49) {
            const int p1 = n / 7, q1 = n - p1 * 7, p2 = m / 7, q2 = m - p2 * 7;
            const int ridx = (p1 - p2 + 6) * 13 + (q1 - q2 + 6);
            v = rpb[ridx * 6 + h] + mask[(size_t)wi * 2401 + n * 49 + m];
        }
        o[(size_t)(wi * 6 + h) * 49 * 64 + t] = f2bf(v);
    }
}

// ============ Kernel A: LN1 + shift/window + MFMA attention + proj + residual ============
__global__ __launch_bounds__(256, 4)
void swin_attn(const float* __restrict__ x, const float* __restrict__ g1,
               const float* __restrict__ b1, const unsigned short* __restrict__ wp,
               const unsigned short* __restrict__ bias_g,
               const float* __restrict__ qkvb, const float* __restrict__ pb,
               float* __restrict__ y)
{
    __shared__ __align__(16) unsigned short q_[64][40];      // 5120 (wave-private rows)
    __shared__ __align__(16) unsigned short o_[64][40];      // 5120 (wave-private rows)
    __shared__ __align__(16) unsigned short k2_[2][64][40];  // 10240 (cross-wave, dbuf)
    __shared__ __align__(16) unsigned short vt2_[2][32][72]; // 9216 (cross-wave, dbuf)
    __shared__ __align__(16) unsigned short p_[64][72];      // 9216 (wave-private rows)
    // total 38912 B -> 4 blocks/CU

    const s16x8* wv = (const s16x8*)wp;
    const int w  = blockIdx.x;
    const int bb = w >> 6, wi = w & 63;
    const int wh = wi >> 3, ww = wi & 7;
    const int tid = threadIdx.x, lane = tid & 63, wave = tid >> 6;
    const int ln = lane & 15, hi = lane >> 4, ko = hi * 8, ro = hi * 4;
    const int m0 = wave * 16;

    // ---- LN1 fully in registers ----
    s16x8 xa[6];
    {
        const int t = m0 + ln;
        const int p = t / 7, q7 = t - p * 7;
        int i2 = wh * 7 + p + 3;  if (i2 >= 56) i2 -= 56;
        int j2 = ww * 7 + q7 + 3; if (j2 >= 56) j2 -= 56;
        const float* xr = x + ((size_t)(bb * 56 + i2) * 56 + j2) * 192;
        ln_frag(xr, g1, b1, hi, xa);
        if (t >= 49) {
            #pragma unroll
            for (int k = 0; k < 6; ++k) xa[k] = s16x8{0,0,0,0,0,0,0,0};
        }
    }

    // QKV for head hh into buffer hh&1 (q_ single: wave-private, consumed before next write)
    auto qkv_head = [&](int hh) {
        const s16x8* wq = wv + ((size_t)(hh * 36) << 6);
        #pragma unroll
        for (int nf = 0; nf < 6; ++nf) {
            s16x8 bf6[6];
            #pragma unroll
            for (int kf = 0; kf < 6; ++kf) bf6[kf] = wq[(nf * 6 + kf) * 64 + lane];
            f32x4 a = f32x4{0.f,0.f,0.f,0.f};
            #pragma unroll
            for (int kf = 0; kf < 6; ++kf)
                a = __builtin_amdgcn_mfma_f32_16x16x32_bf16(xa[kf], bf6[kf], a, 0, 0, 0);
            const int col = nf * 16 + ln;
            #pragma unroll
            for (int i = 0; i < 4; ++i) {
                const int row = m0 + ro + i;
                const float v = a[i];
                if (nf < 2)      q_[row][col]                 = f2bf((v + qkvb[hh*32 + col]) * cSCALE);
                else if (nf < 4) k2_[hh & 1][row][col - 32]   = f2bf(v + qkvb[192 + hh*32 + col - 32]);
                else             vt2_[hh & 1][col - 64][row]  = f2bf(v + qkvb[384 + hh*32 + col - 64]);
            }
        }
    };

    qkv_head(0);

    f32x4 accp[12];
    #pragma unroll
    for (int i = 0; i < 12; ++i) accp[i] = f32x4{0.f,0.f,0.f,0.f};

    for (int h = 0; h < 6; ++h) {
        __syncthreads();   // k2_/vt2_[h&1] visible to all waves

        // ---- S = Q @ K^T + fused bias, softmax (denominator deferred) -> p_ ----
        f32x4 s4[4];
        {
            const s16x8 aq = *(const s16x8*)&q_[m0 + ln][ko];
            #pragma unroll
            for (int nf = 0; nf < 4; ++nf) {
                const s16x8 bk = *(const s16x8*)&k2_[h & 1][nf * 16 + ln][ko];
                s4[nf] = __builtin_amdgcn_mfma_f32_16x16x32_bf16(aq, bk, f32x4{0.f,0.f,0.f,0.f}, 0, 0, 0);
            }
        }
        const unsigned short* bg = bias_g + (size_t)(wi * 6 + h) * 49 * 64;
        float inv4[4];
        #pragma unroll
        for (int i = 0; i < 4; ++i) {
            const int n = m0 + ro + i;
            float b4[4] = {0.f, 0.f, 0.f, 0.f};
            if (n < 49) {
                const uint2 u = *(const uint2*)(bg + n * 64 + ln * 4);
                b4[0] = bf2f((unsigned short)(u.x));
                b4[1] = bf2f((unsigned short)(u.x >> 16));
                b4[2] = bf2f((unsigned short)(u.y));
                b4[3] = bf2f((unsigned short)(u.y >> 16));
            }
            float vv[4];
            #pragma unroll
            for (int nf = 0; nf < 4; ++nf) {
                const int m = nf * 16 + ln;
                vv[nf] = (m >= 49) ? -1e30f : (s4[nf][i] + b4[nf]);
            }
            float mx = fmaxf(fmaxf(vv[0], vv[1]), fmaxf(vv[2], vv[3]));
            #pragma unroll
            for (int o = 1; o < 16; o <<= 1) mx = fmaxf(mx, __shfl_xor(mx, o));
            const float e0 = __expf(vv[0]-mx), e1 = __expf(vv[1]-mx);
            const float e2 = __expf(vv[2]-mx), e3 = __expf(vv[3]-mx);
            float ssum = (e0 + e1) + (e2 + e3);
            #pragma unroll
            for (int o = 1; o < 16; o <<= 1) ssum += __shfl_xor(ssum, o);
            inv4[i] = 1.0f / ssum;
            p_[n][     ln] = f2bf(e0);
            p_[n][16 + ln] = f2bf(e1);
            p_[n][32 + ln] = f2bf(e2);
            p_[n][48 + ln] = f2bf(e3);
        }

        // ---- O = P @ V (unnormalized), scale by inv4 on store -> o_ ----
        f32x4 o2[2];
        o2[0] = f32x4{0.f,0.f,0.f,0.f}; o2[1] = f32x4{0.f,0.f,0.f,0.f};
        #pragma unroll
        for (int kf = 0; kf < 2; ++kf) {
            const s16x8 ap = *(const s16x8*)&p_[m0 + ln][kf * 32 + ko];
            #pragma unroll
            for (int nf = 0; nf < 2; ++nf) {
                const s16x8 bv = *(const s16x8*)&vt2_[h & 1][nf * 16 + ln][kf * 32 + ko];
                o2[nf] = __builtin_amdgcn_mfma_f32_16x16x32_bf16(ap, bv, o2[nf], 0, 0, 0);
            }
        }
        #pragma unroll
        for (int nf = 0; nf < 2; ++nf)
            #pragma unroll
            for (int i = 0; i < 4; ++i)
                o_[m0 + ro + i][nf * 16 + ln] = f2bf(o2[nf][i] * inv4[i]);

        // ---- QKV for next head into other buffer (overlaps this head's tail) ----
        if (h < 5) qkv_head(h + 1);

        // ---- proj partial (o_ wave-private) ----
        {
            const s16x8 ao = *(const s16x8*)&o_[m0 + ln][ko];
            const s16x8* wpj = wv + ((size_t)(216 + h * 12) << 6);
            #pragma unroll
            for (int half = 0; half < 2; ++half) {
                s16x8 bf6[6];
                #pragma unroll
                for (int nf = 0; nf < 6; ++nf) bf6[nf] = wpj[(half * 6 + nf) * 64 + lane];
                #pragma unroll
                for (int nf = 0; nf < 6; ++nf)
                    accp[half * 6 + nf] = __builtin_amdgcn_mfma_f32_16x16x32_bf16(
                        ao, bf6[nf], accp[half * 6 + nf], 0, 0, 0);
            }
        }
    }

    // ---- Epilogue: + proj bias + residual, scatter to shifted coords ----
    #pragma unroll
    for (int i = 0; i < 4; ++i) {
        const int n = m0 + ro + i;
        if (n < 49) {
            const int p = n / 7, q7 = n - p * 7;
            int i2 = wh * 7 + p + 3;  if (i2 >= 56) i2 -= 56;
            int j2 = ww * 7 + q7 + 3; if (j2 >= 56) j2 -= 56;
            const size_t base = ((size_t)(bb * 56 + i2) * 56 + j2) * 192;
            #pragma unroll
            for (int nf = 0; nf < 12; ++nf) {
                const int col = nf * 16 + ln;
                y[base + col] = x[base + col] + pb[col] + accp[nf][i];
            }
        }
    }
}

// stage one 24 KB chunk (fc1_c 12K + fc2_c 12K) into LDS with 512 threads, async
__device__ __forceinline__ void stage24k(const unsigned short* __restrict__ wp, int c,
                                         unsigned short* dst, int tid) {
    const unsigned short* g = wp + (((size_t)(288 + c * 24)) << 9) + tid * 8;
    unsigned short* l = dst + tid * 8;
    #pragma unroll
    for (int i = 0; i < 3; ++i)
        GLDS16(g + i * 4096, l + i * 4096);
}

// ============ Kernel B: LN2 + fc1 + GELU + fc2 + residual (counted-vmcnt pipeline) ============
__global__ __launch_bounds__(512, 4)
void swin_mlp(const float* __restrict__ g2, const float* __restrict__ b2,
              const unsigned short* __restrict__ wp,
              const float* __restrict__ f1b, const float* __restrict__ f2b,
              float* __restrict__ y)
{
    __shared__ __align__(16) unsigned short wbuf[2][12288]; // 49152 B (fc1|fc2 chunk, dbuf)
    __shared__ __align__(16) unsigned short hb[128][40];    // 10240 B (rows wave-private)
    __shared__ float f1b_l[768];                            // 3072 B
    __shared__ float f2b_l[192];                            // 768 B
    // total 63232 B -> 2 blocks/CU (16 waves)

    const int tid = threadIdx.x, lane = tid & 63, wave = tid >> 6;
    const int ln = lane & 15, hi = lane >> 4, ko = hi * 8, ro = hi * 4;
    const int m0 = wave * 16;                    // 0..112
    const size_t r0 = (size_t)blockIdx.x * 128;

    // biases -> LDS (keep global-load FIFO clean inside the loop)
    for (int t = tid; t < 768; t += 512) f1b_l[t] = f1b[t];
    for (int t = tid; t < 192; t += 512) f2b_l[t] = f2b[t];

    // LN2 fully in registers (all global loads consumed here)
    s16x8 xa[6];
    ln_frag(y + (r0 + m0 + ln) * 192, g2, b2, hi, xa);

    // prologue: prefetch chunks 0 and 1 (6 DMA loads outstanding per thread)
    stage24k(wp, 0, wbuf[0], tid);
    stage24k(wp, 1, wbuf[1], tid);
    asm volatile("s_waitcnt lgkmcnt(0)" ::: "memory");   // bias ds_writes committed

    f32x4 acc2[12];
    #pragma unroll
    for (int i = 0; i < 12; ++i) acc2[i] = f32x4{0.f,0.f,0.f,0.f};

    for (int c = 0; c < 24; ++c) {
        // wait for chunk c's 3 loads (leave chunk c+1's 3 in flight); never drain mid-loop
        if (c == 23) asm volatile("s_waitcnt vmcnt(0)" ::: "memory");
        else         asm volatile("s_waitcnt vmcnt(3)" ::: "memory");
        __builtin_amdgcn_s_barrier();

        const s16x8* wb = (const s16x8*)wbuf[c & 1];
        // ---- G1: h_chunk[128x32] = xn @ fc1_c^T ----
        f32x4 acc1[2];
        acc1[0] = f32x4{0.f,0.f,0.f,0.f}; acc1[1] = f32x4{0.f,0.f,0.f,0.f};
        #pragma unroll
        for (int kf = 0; kf < 6; ++kf) {
            #pragma unroll
            for (int nf = 0; nf < 2; ++nf)
                acc1[nf] = __builtin_amdgcn_mfma_f32_16x16x32_bf16(
                    xa[kf], wb[(nf * 6 + kf) * 64 + lane], acc1[nf], 0, 0, 0);
        }
        // ---- bias + GELU -> hb (wave-private rows) ----
        #pragma unroll
        for (int nf = 0; nf < 2; ++nf) {
            const int col = nf * 16 + ln;
            const float bias = f1b_l[c * 32 + col];
            #pragma unroll
            for (int i = 0; i < 4; ++i)
                hb[m0 + ro + i][col] = f2bf(gelu_f(acc1[nf][i] + bias));
        }
        // ---- G2: out += h_chunk @ fc2_c^T ----
        const s16x8 ah = *(const s16x8*)&hb[m0 + ln][ko];
        #pragma unroll
        for (int nf = 0; nf < 12; ++nf)
            acc2[nf] = __builtin_amdgcn_mfma_f32_16x16x32_bf16(
                ah, wb[(12 + nf) * 64 + lane], acc2[nf], 0, 0, 0);

        if (c < 23) {
            __builtin_amdgcn_s_barrier();          // all waves done reading wbuf[c&1]
            if (c < 22) stage24k(wp, c + 2, wbuf[c & 1], tid);
        }
    }

    // ---- Epilogue: + fc2 bias + residual (in-place) ----
    #pragma unroll
    for (int i = 0; i < 4; ++i) {
        const int row = m0 + ro + i;
        float* yp = y + (r0 + row) * 192;
        #pragma unroll
        for (int nf = 0; nf < 12; ++nf) {
            const int col = nf * 16 + ln;
            yp[col] = yp[col] + f2b_l[col] + acc2[nf][i];
        }
    }
}

extern "C" void kernel_launch(void* const* d_in, const int* in_sizes, int n_in,
                              void* d_out, int out_size, void* d_ws, size_t ws_size,
                              hipStream_t stream) {
    (void)in_sizes; (void)n_in; (void)ws_size; (void)out_size;
    const float* x    = (const float*)d_in[0];
    const float* mask = (const float*)d_in[1];
    const float* g1   = (const float*)d_in[2];
    const float* b1   = (const float*)d_in[3];
    const float* qkvw = (const float*)d_in[4];
    const float* qkvb = (const float*)d_in[5];
    const float* rpb  = (const float*)d_in[6];
    const float* pw   = (const float*)d_in[7];
    const float* pb   = (const float*)d_in[8];
    const float* g2   = (const float*)d_in[9];
    const float* b2   = (const float*)d_in[10];
    const float* f1w  = (const float*)d_in[11];
    const float* f1b  = (const float*)d_in[12];
    const float* f2w  = (const float*)d_in[13];
    const float* f2b  = (const float*)d_in[14];
    float* y = (float*)d_out;
    unsigned short* wpk  = (unsigned short*)d_ws;   // 884,736 B
    unsigned short* bias = wpk + 442368;            // 2,408,448 B -> ~3.3 MB total

    pack_w<<<dim3(216), dim3(256), 0, stream>>>(qkvw, pw, f1w, f2w, wpk);
    pack_bias<<<dim3(384), dim3(256), 0, stream>>>(mask, rpb, bias);
    swin_attn<<<dim3(64 * 64), dim3(256), 0, stream>>>(
        x, g1, b1, wpk, bias, qkvb, pb, y);
    swin_mlp<<<dim3(1568), dim3(512), 0, stream>>>(
        g2, b2, wpk, f1b, f2b, y);
}